// Round 7
// baseline (344.900 us; speedup 1.0000x reference)
//
#include <hip/hip_runtime.h>
#include <hip/hip_bf16.h>

// Problem: B=2, S=2048, D=2048, H=16, HD=128
#define B_  2
#define S_  2048
#define D_  2048
#define H_  16
#define HD_ 128

typedef unsigned short u16;
typedef __attribute__((ext_vector_type(8))) short bf16x8;
typedef __attribute__((ext_vector_type(4))) float f32x4;
typedef __attribute__((ext_vector_type(16))) float f32x16;

#define GLOAD_LDS16(g, l)                                                     \
  __builtin_amdgcn_global_load_lds(                                           \
      (const __attribute__((address_space(1))) void*)(g),                     \
      (__attribute__((address_space(3))) void*)(l), 16, 0, 0)

#define BAR()  asm volatile("s_barrier" ::: "memory")

__device__ __forceinline__ u16 f2bf(float f){
  unsigned u; __builtin_memcpy(&u, &f, 4);
  u += 0x7fffu + ((u >> 16) & 1u);     // round-to-nearest-even
  return (u16)(u >> 16);
}
__device__ __forceinline__ float bf2f(u16 h){
  unsigned u = ((unsigned)h) << 16; float f; __builtin_memcpy(&f, &u, 4); return f;
}
__device__ __forceinline__ unsigned pack_bf16x2(float lo, float hi){
  __hip_bfloat162 h2 = __float22bfloat162_rn(float2{lo, hi});  // v_cvt_pk_bf16_f32
  unsigned u; __builtin_memcpy(&u, &h2, 4); return u;
}

// ---------------- cast x (fp32 -> bf16) ----------------
__global__ void cast_x_kernel(const float* __restrict__ x, u16* __restrict__ xb){
  int i = blockIdx.x * 256 + threadIdx.x;            // 2,097,152 float4s
  float4 v = reinterpret_cast<const float4*>(x)[i];
  ushort4 o; o.x = f2bf(v.x); o.y = f2bf(v.y); o.z = f2bf(v.z); o.w = f2bf(v.w);
  reinterpret_cast<ushort4*>(xb)[i] = o;
}

// ---------------- transpose + cast weights: Wt[n][k] = W[k][n] ----------------
__global__ void wtrans_kernel(const float* __restrict__ w0, const float* __restrict__ w1,
                              const float* __restrict__ w2, const float* __restrict__ w3,
                              u16* __restrict__ o0, u16* __restrict__ o1,
                              u16* __restrict__ o2, u16* __restrict__ o3){
  __shared__ float t[32][33];
  const float* src; u16* dst;
  switch (blockIdx.z){
    case 0:  src = w0; dst = o0; break;
    case 1:  src = w1; dst = o1; break;
    case 2:  src = w2; dst = o2; break;
    default: src = w3; dst = o3; break;
  }
  int j0 = blockIdx.x * 32, i0 = blockIdx.y * 32;
  int tx = threadIdx.x & 31, ty = threadIdx.x >> 5;   // 256 thr: 32 x 8
  #pragma unroll
  for (int rr = 0; rr < 4; ++rr)
    t[ty + rr*8][tx] = src[(size_t)(i0 + ty + rr*8) * D_ + j0 + tx];
  __syncthreads();
  #pragma unroll
  for (int rr = 0; rr < 4; ++rr)
    dst[(size_t)(j0 + ty + rr*8) * D_ + i0 + tx] = f2bf(t[tx][ty + rr*8]);
}

// ======= 256x128, BK=64, 8 waves (4Mx2N), triple-buffer, 2-tile-deep prefetch =======
// LDS layout [buf][row][64k] bf16 (128B rows) with 16B-slot XOR swizzle slot^=(row&7):
//  - ds_read_b128 column slices hit all 32 banks (2 lanes/bank = free);
//  - global_load_lds keeps a LINEAR dest; the global SOURCE is inverse-swizzled.
// Ledger (provably safe): during tile t, phases 0-2 issue the 3 units (A0,A1,B) of
// tile t+2 into buf (t+2)%3 (read by nobody until t+2 -> no WAR). Phase 3 does
// vmcnt(6): retires exactly tile t+1's 6 loads (issued during t-1), leaves t+2's 6
// in flight across the barrier. Mid-loop never drains to 0; tail tiles drain.
// MODE 0: QKV fused (768 blocks = 3 exact generations), scatter epilogue.
// MODE 1: O-projection (256 blocks = 1 generation), fp32 epilogue.
template<int MODE>
__global__ __launch_bounds__(512) void gemm_bigk_kernel(
    const u16* __restrict__ A,
    const u16* __restrict__ B0, const u16* __restrict__ B1, const u16* __restrict__ B2,
    u16* __restrict__ qb, u16* __restrict__ kb, u16* __restrict__ vtb,
    float* __restrict__ outp)
{
  constexpr int K  = 2048;
  constexpr int NT = K / 64;                 // 32 K-tiles
  __shared__ u16 Als[3][2][128 * 64];        // 96 KB  [buf][half][row*64+k]
  __shared__ u16 Bls[3][128 * 64];           // 48 KB

  // XCD-bijective swizzle; nt-contiguous per XCD for B-panel L2 locality
  const int bid = blockIdx.x;
  const int swz = (MODE == 0) ? ((bid & 7) * 96 + (bid >> 3))
                              : ((bid & 7) * 32 + (bid >> 3));
  const int mt = swz & 15, nt = swz >> 4;    // 16 m-tiles x (48 | 16) n-tiles
  const int m0 = mt * 256;
  const int which = (MODE == 0) ? (nt >> 4) : 0;
  const u16* Bmat = (MODE == 1) ? B0 : ((which == 0) ? B0 : ((which == 1) ? B1 : B2));
  const int n0 = (MODE == 0) ? ((nt & 15) * 128) : (nt * 128);

  const int tid  = threadIdx.x;
  const int lane = tid & 63;
  const int wid  = tid >> 6;
  const int wr = wid >> 1, wc = wid & 1;     // wave tile: rows wr*64+, cols wc*64+
  const int g = lane >> 4, r16 = lane & 15;
  const int ha = wr >> 1;                    // this wave's A half
  const int sx = r16 & 7;                    // read-side slot XOR

  f32x4 acc[4][4];
  #pragma unroll
  for (int i = 0; i < 4; ++i)
    #pragma unroll
    for (int j = 0; j < 4; ++j) acc[i][j] = f32x4{0.f, 0.f, 0.f, 0.f};

  // ---- staging: 2 chunks/thread per unit; chunk c = rd*512+tid -> row=c>>3, slot=c&7
  auto stageA = [&](int b, int h, int kt){
    #pragma unroll
    for (int rd = 0; rd < 2; ++rd){
      int c = rd * 512 + tid;
      int row = c >> 3, sl = c & 7;
      GLOAD_LDS16(A + (size_t)(m0 + h * 128 + row) * K + kt + ((sl ^ (row & 7)) * 8),
                  &Als[b][h][(rd * 512 + wid * 64) * 8]);
    }
  };
  auto stageB = [&](int b, int kt){
    #pragma unroll
    for (int rd = 0; rd < 2; ++rd){
      int c = rd * 512 + tid;
      int row = c >> 3, sl = c & 7;
      GLOAD_LDS16(Bmat + (size_t)(n0 + row) * K + kt + ((sl ^ (row & 7)) * 8),
                  &Bls[b][(rd * 512 + wid * 64) * 8]);
    }
  };
  auto rdA = [&](int b, int fi, int ks)->bf16x8 {
    int lr = (wr & 1) * 64 + fi * 16 + r16;
    int sp = (ks * 4 + g) ^ sx;
    return *reinterpret_cast<const bf16x8*>(&Als[b][ha][lr * 64 + sp * 8]);
  };
  auto rdB = [&](int b, int fj, int ks)->bf16x8 {
    int rowb = wc * 64 + fj * 16 + r16;
    int sp = (ks * 4 + g) ^ sx;
    return *reinterpret_cast<const bf16x8*>(&Bls[b][rowb * 64 + sp * 8]);
  };

  // prologue: tiles 0,1 staged; vmcnt(6) retires tile 0's units, leaves tile 1's
  stageA(0, 0, 0);  stageA(0, 1, 0);  stageB(0, 0);
  stageA(1, 0, 64); stageA(1, 1, 64); stageB(1, 64);
  asm volatile("s_waitcnt vmcnt(6)" ::: "memory");
  BAR();

  for (int t = 0; t < NT; ++t){
    const int b  = t % 3;
    const int bn = (t + 2) % 3;
    const int ktn = (t + 2) * 64;
    const bool pf = (t + 2 < NT);
    bf16x8 a0k0, a0k1, a1k0, a1k1, b0k0, b0k1, b1k0, b1k1;

    // ---- phase 0: acc[0..1][0..1] ----
    a0k0 = rdA(b, 0, 0); a0k1 = rdA(b, 0, 1);
    a1k0 = rdA(b, 1, 0); a1k1 = rdA(b, 1, 1);
    b0k0 = rdB(b, 0, 0); b0k1 = rdB(b, 0, 1);
    b1k0 = rdB(b, 1, 0); b1k1 = rdB(b, 1, 1);
    if (pf) stageA(bn, 0, ktn);
    BAR();
    __builtin_amdgcn_s_setprio(1);
    acc[0][0] = __builtin_amdgcn_mfma_f32_16x16x32_bf16(a0k0, b0k0, acc[0][0], 0, 0, 0);
    acc[0][0] = __builtin_amdgcn_mfma_f32_16x16x32_bf16(a0k1, b0k1, acc[0][0], 0, 0, 0);
    acc[0][1] = __builtin_amdgcn_mfma_f32_16x16x32_bf16(a0k0, b1k0, acc[0][1], 0, 0, 0);
    acc[0][1] = __builtin_amdgcn_mfma_f32_16x16x32_bf16(a0k1, b1k1, acc[0][1], 0, 0, 0);
    acc[1][0] = __builtin_amdgcn_mfma_f32_16x16x32_bf16(a1k0, b0k0, acc[1][0], 0, 0, 0);
    acc[1][0] = __builtin_amdgcn_mfma_f32_16x16x32_bf16(a1k1, b0k1, acc[1][0], 0, 0, 0);
    acc[1][1] = __builtin_amdgcn_mfma_f32_16x16x32_bf16(a1k0, b1k0, acc[1][1], 0, 0, 0);
    acc[1][1] = __builtin_amdgcn_mfma_f32_16x16x32_bf16(a1k1, b1k1, acc[1][1], 0, 0, 0);
    __builtin_amdgcn_s_setprio(0);

    // ---- phase 1: acc[2..3][0..1] ----
    a0k0 = rdA(b, 2, 0); a0k1 = rdA(b, 2, 1);
    a1k0 = rdA(b, 3, 0); a1k1 = rdA(b, 3, 1);
    if (pf) stageA(bn, 1, ktn);
    BAR();
    __builtin_amdgcn_s_setprio(1);
    acc[2][0] = __builtin_amdgcn_mfma_f32_16x16x32_bf16(a0k0, b0k0, acc[2][0], 0, 0, 0);
    acc[2][0] = __builtin_amdgcn_mfma_f32_16x16x32_bf16(a0k1, b0k1, acc[2][0], 0, 0, 0);
    acc[2][1] = __builtin_amdgcn_mfma_f32_16x16x32_bf16(a0k0, b1k0, acc[2][1], 0, 0, 0);
    acc[2][1] = __builtin_amdgcn_mfma_f32_16x16x32_bf16(a0k1, b1k1, acc[2][1], 0, 0, 0);
    acc[3][0] = __builtin_amdgcn_mfma_f32_16x16x32_bf16(a1k0, b0k0, acc[3][0], 0, 0, 0);
    acc[3][0] = __builtin_amdgcn_mfma_f32_16x16x32_bf16(a1k1, b0k1, acc[3][0], 0, 0, 0);
    acc[3][1] = __builtin_amdgcn_mfma_f32_16x16x32_bf16(a1k0, b1k0, acc[3][1], 0, 0, 0);
    acc[3][1] = __builtin_amdgcn_mfma_f32_16x16x32_bf16(a1k1, b1k1, acc[3][1], 0, 0, 0);
    __builtin_amdgcn_s_setprio(0);

    // ---- phase 2: acc[0..1][2..3] ----
    a0k0 = rdA(b, 0, 0); a0k1 = rdA(b, 0, 1);
    a1k0 = rdA(b, 1, 0); a1k1 = rdA(b, 1, 1);
    b0k0 = rdB(b, 2, 0); b0k1 = rdB(b, 2, 1);
    b1k0 = rdB(b, 3, 0); b1k1 = rdB(b, 3, 1);
    if (pf) stageB(bn, ktn);
    BAR();
    __builtin_amdgcn_s_setprio(1);
    acc[0][2] = __builtin_amdgcn_mfma_f32_16x16x32_bf16(a0k0, b0k0, acc[0][2], 0, 0, 0);
    acc[0][2] = __builtin_amdgcn_mfma_f32_16x16x32_bf16(a0k1, b0k1, acc[0][2], 0, 0, 0);
    acc[0][3] = __builtin_amdgcn_mfma_f32_16x16x32_bf16(a0k0, b1k0, acc[0][3], 0, 0, 0);
    acc[0][3] = __builtin_amdgcn_mfma_f32_16x16x32_bf16(a0k1, b1k1, acc[0][3], 0, 0, 0);
    acc[1][2] = __builtin_amdgcn_mfma_f32_16x16x32_bf16(a1k0, b0k0, acc[1][2], 0, 0, 0);
    acc[1][2] = __builtin_amdgcn_mfma_f32_16x16x32_bf16(a1k1, b0k1, acc[1][2], 0, 0, 0);
    acc[1][3] = __builtin_amdgcn_mfma_f32_16x16x32_bf16(a1k0, b1k0, acc[1][3], 0, 0, 0);
    acc[1][3] = __builtin_amdgcn_mfma_f32_16x16x32_bf16(a1k1, b1k1, acc[1][3], 0, 0, 0);
    __builtin_amdgcn_s_setprio(0);

    // ---- phase 3: acc[2..3][2..3]; counted-vmcnt tile boundary ----
    a0k0 = rdA(b, 2, 0); a0k1 = rdA(b, 2, 1);
    a1k0 = rdA(b, 3, 0); a1k1 = rdA(b, 3, 1);
    if (pf) asm volatile("s_waitcnt vmcnt(6)" ::: "memory");
    else    asm volatile("s_waitcnt vmcnt(0)" ::: "memory");
    BAR();
    __builtin_amdgcn_s_setprio(1);
    acc[2][2] = __builtin_amdgcn_mfma_f32_16x16x32_bf16(a0k0, b0k0, acc[2][2], 0, 0, 0);
    acc[2][2] = __builtin_amdgcn_mfma_f32_16x16x32_bf16(a0k1, b0k1, acc[2][2], 0, 0, 0);
    acc[2][3] = __builtin_amdgcn_mfma_f32_16x16x32_bf16(a0k0, b1k0, acc[2][3], 0, 0, 0);
    acc[2][3] = __builtin_amdgcn_mfma_f32_16x16x32_bf16(a0k1, b1k1, acc[2][3], 0, 0, 0);
    acc[3][2] = __builtin_amdgcn_mfma_f32_16x16x32_bf16(a1k0, b0k0, acc[3][2], 0, 0, 0);
    acc[3][2] = __builtin_amdgcn_mfma_f32_16x16x32_bf16(a1k1, b0k1, acc[3][2], 0, 0, 0);
    acc[3][3] = __builtin_amdgcn_mfma_f32_16x16x32_bf16(a1k0, b1k0, acc[3][3], 0, 0, 0);
    acc[3][3] = __builtin_amdgcn_mfma_f32_16x16x32_bf16(a1k1, b1k1, acc[3][3], 0, 0, 0);
    __builtin_amdgcn_s_setprio(0);
  }

  // epilogue; C layout: col = lane&15, row = (lane>>4)*4 + e
  #pragma unroll
  for (int i = 0; i < 4; ++i){
    int row0 = m0 + wr*64 + i*16 + g*4;
    int b2  = row0 >> 11, s0 = row0 & (S_ - 1);
    #pragma unroll
    for (int j = 0; j < 4; ++j){
      int col = n0 + wc*64 + j*16 + r16;
      if (MODE == 1){
        #pragma unroll
        for (int e = 0; e < 4; ++e)
          outp[(size_t)(row0 + e) * D_ + col] = acc[i][j][e];
      } else {
        int h2 = col >> 7, dd = col & 127;
        int bh = b2 * H_ + h2;
        if (which == 2){
          ushort4 pk;
          pk.x = f2bf(acc[i][j][0]); pk.y = f2bf(acc[i][j][1]);
          pk.z = f2bf(acc[i][j][2]); pk.w = f2bf(acc[i][j][3]);
          *reinterpret_cast<ushort4*>(&vtb[((size_t)bh * HD_ + dd) * S_ + s0]) = pk;
        } else {
          u16* dstb = (which == 0) ? qb : kb;
          #pragma unroll
          for (int e = 0; e < 4; ++e)
            dstb[((size_t)bh * S_ + s0 + e) * HD_ + dd] = f2bf(acc[i][j][e]);
        }
      }
    }
  }
}

// ---------------- RoPE in place on q/k [bh][s][128] ----------------
__global__ void rope_kernel(u16* __restrict__ qbuf, u16* __restrict__ kbuf){
  int idx = blockIdx.x * 256 + threadIdx.x;   // 32*2048*64 threads
  int j  = idx & 63;
  int s  = (idx >> 6) & (S_ - 1);
  int bh = idx >> 17;
  const float LOG2_1E4 = 13.287712379549449f;
  float inv = exp2f(-(float)(2 * j) * (LOG2_1E4 / 128.f));
  float ang = (float)s * inv;
  float sn = __sinf(ang), cs = __cosf(ang);
  size_t base = ((size_t)bh * S_ + s) * HD_;
  float x1 = bf2f(qbuf[base + j]), x2 = bf2f(qbuf[base + 64 + j]);
  qbuf[base + j]      = f2bf(x1 * cs - x2 * sn);
  qbuf[base + 64 + j] = f2bf(x2 * cs + x1 * sn);
  float y1 = bf2f(kbuf[base + j]), y2 = bf2f(kbuf[base + 64 + j]);
  kbuf[base + j]      = f2bf(y1 * cs - y2 * sn);
  kbuf[base + 64 + j] = f2bf(y2 * cs + y1 * sn);
}

// ---------------- attention v5: flash-style LDS-shared K/V, double-buffered ----------
__global__ __launch_bounds__(256) void attn5_kernel(
  const u16* __restrict__ qbuf, const u16* __restrict__ kbuf,
  const u16* __restrict__ vtb,  u16* __restrict__ ob)
{
  __shared__ u16 Klds[2][32 * 128];   // 8 KB per buffer
  __shared__ u16 Vlds[2][128 * 32];   // 8 KB per buffer

  const int lane = threadIdx.x & 63;
  const int wid  = threadIdx.x >> 6;     // 0..3 = q-chunk within block
  const int r    = lane & 31;
  const int hi   = lane >> 5;
  const int bh   = blockIdx.x;
  const int qblk = 15 - blockIdx.y;      // heavy blocks dispatched first
  const int qc   = qblk * 128 + wid * 32;
  const int cend = 4 * qblk + wid;       // this wave's diagonal kv tile
  const int tmax = 4 * qblk + 3;         // last tile staged by the block

  const float SCALE = 0.08838834764831845f;  // 1/sqrt(128)

  const size_t sbase = (size_t)bh * S_ * HD_;
  const size_t vbase = (size_t)bh * HD_ * S_;

  // Q fragments: lane holds Q[qc+r][d = cc*16 + hi*8 + j]
  bf16x8 qf[8];
  {
    const u16* qrow = qbuf + sbase + (size_t)(qc + r) * HD_ + hi * 8;
    #pragma unroll
    for (int cc = 0; cc < 8; ++cc)
      qf[cc] = *reinterpret_cast<const bf16x8*>(qrow + cc * 16);
  }

  f32x16 oacc[4];
  #pragma unroll
  for (int i = 0; i < 4; ++i)
    #pragma unroll
    for (int j = 0; j < 16; ++j) oacc[i][j] = 0.f;
  float lsum = 0.f;

  auto stage = [&](int buf, int t){
    const int kv0 = t * 32;
    u16* Kt = &Klds[buf][0];
    u16* Vt = &Vlds[buf][0];
    #pragma unroll
    for (int j = 0; j < 2; ++j){
      const int cbase = wid * 64 + j * 256;   // wave-uniform
      const int ck = cbase + lane;
      const int krow = ck >> 4, kslot = ck & 15;
      GLOAD_LDS16(kbuf + sbase + (size_t)(kv0 + krow) * HD_ + ((kslot ^ (krow & 15)) * 8),
                  Kt + cbase * 8);
      const int vd = ck >> 2, vslot = ck & 3;
      GLOAD_LDS16(vtb + vbase + (size_t)vd * S_ + kv0 + ((vslot ^ ((vd >> 1) & 3)) * 8),
                  Vt + cbase * 8);
    }
  };

  stage(0, 0);
  asm volatile("s_waitcnt vmcnt(0)" ::: "memory");
  __syncthreads();

  for (int t = 0; t <= tmax; ++t){
    const int cur = t & 1;
    if (t < tmax) stage(cur ^ 1, t + 1);

    if (t <= cend){
      const bool diag = (t == cend);
      f32x16 sc;
      #pragma unroll
      for (int j = 0; j < 16; ++j) sc[j] = 0.f;
      const u16* Kt = &Klds[cur][0];
      #pragma unroll
      for (int cc = 0; cc < 8; ++cc){
        const int slot = (cc * 2 + hi) ^ (r & 15);
        bf16x8 kf = *reinterpret_cast<const bf16x8*>(&Kt[r * 128 + slot * 8]);
        sc = __builtin_amdgcn_mfma_f32_32x32x16_bf16(kf, qf[cc], sc, 0, 0, 0);
      }
      float p[16];
      #pragma unroll
      for (int reg = 0; reg < 16; ++reg){
        float tt = sc[reg] * SCALE;
        float u  = tt * tt * 4.0e-4f;
        float capped = tt * (1.f - u * 0.33333333f + u * u * 0.13333333f);
        float pv = __expf(capped);
        if (diag){
          int kl = (reg & 3) + 8 * (reg >> 2) + 4 * hi;
          if (kl > r) pv = 0.f;
        }
        p[reg] = pv;
        lsum += pv;
      }
      unsigned a[4], b[4];
      #pragma unroll
      for (int r4 = 0; r4 < 4; ++r4){
        a[r4] = pack_bf16x2(p[r4*4+0], p[r4*4+1]);
        b[r4] = pack_bf16x2(p[r4*4+2], p[r4*4+3]);
      }
      unsigned ra0 = __shfl_xor(hi ? a[0] : a[1], 32);
      unsigned rb0 = __shfl_xor(hi ? b[0] : b[1], 32);
      unsigned ra1 = __shfl_xor(hi ? a[2] : a[3], 32);
      unsigned rb1 = __shfl_xor(hi ? b[2] : b[3], 32);
      unsigned pw[8];
      pw[0] = hi ? ra0 : a[0];  pw[1] = hi ? rb0 : b[0];
      pw[2] = hi ? a[1] : ra0;  pw[3] = hi ? b[1] : rb0;
      pw[4] = hi ? ra1 : a[2];  pw[5] = hi ? rb1 : b[2];
      pw[6] = hi ? a[3] : ra1;  pw[7] = hi ? b[3] : rb1;
      bf16x8 pb0, pb1;
      __builtin_memcpy(&pb0, &pw[0], 16);
      __builtin_memcpy(&pb1, &pw[4], 16);
      const u16* Vt = &Vlds[cur][0];
      #pragma unroll
      for (int i = 0; i < 4; ++i){
        const int d  = i * 32 + r;
        const int sw = (d >> 1) & 3;
        bf16x8 vf0 = *reinterpret_cast<const bf16x8*>(&Vt[d * 32 + (hi ^ sw) * 8]);
        oacc[i] = __builtin_amdgcn_mfma_f32_32x32x16_bf16(vf0, pb0, oacc[i], 0, 0, 0);
        bf16x8 vf1 = *reinterpret_cast<const bf16x8*>(&Vt[d * 32 + ((2 + hi) ^ sw) * 8]);
        oacc[i] = __builtin_amdgcn_mfma_f32_32x32x16_bf16(vf1, pb1, oacc[i], 0, 0, 0);
      }
    }
    asm volatile("s_waitcnt vmcnt(0)" ::: "memory");
    __syncthreads();
  }

  float lt = lsum + __shfl_xor(lsum, 32);
  float linv = 1.0f / (1.0f + lt);       // +1 = sink term exp(-m), m=0

  const int b = bh >> 4, h = bh & 15;
  u16* orow = ob + ((size_t)(b * S_ + qc + r)) * D_ + h * HD_;
  #pragma unroll
  for (int i = 0; i < 4; ++i){
    #pragma unroll
    for (int r4 = 0; r4 < 4; ++r4){
      ushort4 st;
      st.x = f2bf(oacc[i][r4*4+0] * linv);
      st.y = f2bf(oacc[i][r4*4+1] * linv);
      st.z = f2bf(oacc[i][r4*4+2] * linv);
      st.w = f2bf(oacc[i][r4*4+3] * linv);
      *reinterpret_cast<ushort4*>(orow + i*32 + r4*8 + hi*4) = st;
    }
  }
}

extern "C" void kernel_launch(void* const* d_in, const int* in_sizes, int n_in,
                              void* d_out, int out_size, void* d_ws, size_t ws_size,
                              hipStream_t stream){
  const float* x  = (const float*)d_in[0];
  const float* Wq = (const float*)d_in[1];
  const float* Wk = (const float*)d_in[2];
  const float* Wv = (const float*)d_in[3];
  const float* Wo = (const float*)d_in[4];
  float* out = (float*)d_out;
  char* ws = (char*)d_ws;

  // workspace layout (112 MB total)
  u16* xb   = (u16*)(ws);                      // 16 MB  x bf16 [4096][2048]
  u16* wtq  = (u16*)(ws + (size_t)(16u << 20));//  8 MB  Wq^T bf16 [N][K]
  u16* wtk  = (u16*)(ws + (size_t)(24u << 20));
  u16* wtv  = (u16*)(ws + (size_t)(32u << 20));
  u16* wto  = (u16*)(ws + (size_t)(40u << 20));
  u16* qbuf = (u16*)(ws + (size_t)(48u << 20));// 16 MB  [bh][s][128]
  u16* kbuf = (u16*)(ws + (size_t)(64u << 20));// 16 MB  [bh][s][128]
  u16* vtb  = (u16*)(ws + (size_t)(80u << 20));// 16 MB  [bh][128][s]
  u16* atb  = (u16*)(ws + (size_t)(96u << 20));// 16 MB  [b*S+s][h*128+d]

  cast_x_kernel<<<8192, 256, 0, stream>>>(x, xb);
  wtrans_kernel<<<dim3(64, 64, 4), 256, 0, stream>>>(Wq, Wk, Wv, Wo, wtq, wtk, wtv, wto);
  gemm_bigk_kernel<0><<<768, 512, 0, stream>>>(xb, wtq, wtk, wtv,
                                               qbuf, kbuf, vtb, nullptr);
  rope_kernel<<<16384, 256, 0, stream>>>(qbuf, kbuf);
  attn5_kernel<<<dim3(32, 16), 256, 0, stream>>>(qbuf, kbuf, vtb, atb);
  gemm_bigk_kernel<1><<<256, 512, 0, stream>>>(atb, wto, nullptr, nullptr,
                                               nullptr, nullptr, nullptr, out);
}

// Round 8
// 326.607 us; speedup vs baseline: 1.0560x; 1.0560x over previous
//
#include <hip/hip_runtime.h>
#include <hip/hip_bf16.h>

// Problem: B=2, S=2048, D=2048, H=16, HD=128
#define B_  2
#define S_  2048
#define D_  2048
#define H_  16
#define HD_ 128

typedef unsigned short u16;
typedef __attribute__((ext_vector_type(8))) short bf16x8;
typedef __attribute__((ext_vector_type(4))) float f32x4;
typedef __attribute__((ext_vector_type(16))) float f32x16;

#define GLOAD_LDS16(g, l)                                                     \
  __builtin_amdgcn_global_load_lds(                                           \
      (const __attribute__((address_space(1))) void*)(g),                     \
      (__attribute__((address_space(3))) void*)(l), 16, 0, 0)

#define BAR()   asm volatile("s_barrier" ::: "memory")
#define PRIO1() __builtin_amdgcn_s_setprio(1)
#define PRIO0() __builtin_amdgcn_s_setprio(0)

__device__ __forceinline__ u16 f2bf(float f){
  unsigned u; __builtin_memcpy(&u, &f, 4);
  u += 0x7fffu + ((u >> 16) & 1u);     // round-to-nearest-even
  return (u16)(u >> 16);
}
__device__ __forceinline__ float bf2f(u16 h){
  unsigned u = ((unsigned)h) << 16; float f; __builtin_memcpy(&f, &u, 4); return f;
}
__device__ __forceinline__ unsigned pack_bf16x2(float lo, float hi){
  __hip_bfloat162 h2 = __float22bfloat162_rn(float2{lo, hi});  // v_cvt_pk_bf16_f32
  unsigned u; __builtin_memcpy(&u, &h2, 4); return u;
}

// ---------------- cast x (fp32 -> bf16) ----------------
__global__ void cast_x_kernel(const float* __restrict__ x, u16* __restrict__ xb){
  int i = blockIdx.x * 256 + threadIdx.x;            // 2,097,152 float4s
  float4 v = reinterpret_cast<const float4*>(x)[i];
  ushort4 o; o.x = f2bf(v.x); o.y = f2bf(v.y); o.z = f2bf(v.z); o.w = f2bf(v.w);
  reinterpret_cast<ushort4*>(xb)[i] = o;
}

// ---------------- transpose + cast weights: Wt[n][k] = W[k][n] ----------------
__global__ void wtrans_kernel(const float* __restrict__ w0, const float* __restrict__ w1,
                              const float* __restrict__ w2, const float* __restrict__ w3,
                              u16* __restrict__ o0, u16* __restrict__ o1,
                              u16* __restrict__ o2, u16* __restrict__ o3){
  __shared__ float t[32][33];
  const float* src; u16* dst;
  switch (blockIdx.z){
    case 0:  src = w0; dst = o0; break;
    case 1:  src = w1; dst = o1; break;
    case 2:  src = w2; dst = o2; break;
    default: src = w3; dst = o3; break;
  }
  int j0 = blockIdx.x * 32, i0 = blockIdx.y * 32;
  int tx = threadIdx.x & 31, ty = threadIdx.x >> 5;   // 256 thr: 32 x 8
  #pragma unroll
  for (int rr = 0; rr < 4; ++rr)
    t[ty + rr*8][tx] = src[(size_t)(i0 + ty + rr*8) * D_ + j0 + tx];
  __syncthreads();
  #pragma unroll
  for (int rr = 0; rr < 4; ++rr)
    dst[(size_t)(j0 + ty + rr*8) * D_ + i0 + tx] = f2bf(t[tx][ty + rr*8]);
}

// ======= QKV GEMM: 256x256, BK=64, 8 waves (2Mx4N, wave out 128x64), 8-phase =======
// m201 geometry: acc[8][4] (128 VGPR), 64 MFMA : 24 ds_read_b128 per K-tile per wave.
// LDS 128 KB: [dbuf][half][128 rows][64 k] bf16, 16B-slot XOR swizzle slot^=(row&7)
// on BOTH the pre-swizzled global source (linear gload_lds dest) and the ds_read
// side (R6-measured: 0 bank conflicts). 8 phases per 2 K-tiles (ta=buf0, tb=buf1),
// 16 MFMA each; B-frags b01/b23 kept in regs so p3/p7 read nothing.
// Counted-vmcnt ledger (never drains mid-loop): stage stream per iter
//   p0: tbB(4 loads)  p3: naA(4)  p4: naB(4)  p7: nbA(4)   [na=2i+2, nb=2i+3]
// vmcnt(4) at p3-end (retires tbA+tbB; 12->4 in flight) and p7-end (retires
// naA+naB). Every stage-write is >=1 barrier after its buffer's last read.
__global__ __launch_bounds__(512) void gemm256p8_kernel(
    const u16* __restrict__ A,
    const u16* __restrict__ B0, const u16* __restrict__ B1, const u16* __restrict__ B2,
    u16* __restrict__ qb, u16* __restrict__ kb, u16* __restrict__ vtb)
{
  constexpr int K = 2048;
  constexpr int NITER = K / 128;             // 16 iterations x 2 K-tiles
  __shared__ u16 Als[2][2][128 * 64];        // 64 KB
  __shared__ u16 Bls[2][2][128 * 64];        // 64 KB

  // XCD-bijective swizzle (384 = 8*48); nt-contiguous per XCD for B-panel reuse
  const int bid = blockIdx.x;
  const int swz = (bid & 7) * 48 + (bid >> 3);
  const int mt = swz & 15, nt = swz >> 4;    // 16 m-tiles x 24 n-tiles
  const int m0 = mt * 256;
  const int which = nt >> 3;                 // 0:q 1:k 2:v
  const u16* Bmat = (which == 0) ? B0 : ((which == 1) ? B1 : B2);
  const int n0 = (nt & 7) * 256;

  const int tid  = threadIdx.x;
  const int lane = tid & 63;
  const int wid  = tid >> 6;
  const int wr = wid >> 2, wc = wid & 3;     // wave out: rows wr*128+[0,128), cols wc*64+[0,64)
  const int g = lane >> 4, r16 = lane & 15;
  const int sx = r16 & 7;

  f32x4 acc[8][4];
  #pragma unroll
  for (int i = 0; i < 8; ++i)
    #pragma unroll
    for (int j = 0; j < 4; ++j) acc[i][j] = f32x4{0.f, 0.f, 0.f, 0.f};

  // stage one half-tile (128 rows x 64 k = 16 KB): 2 loads/thread
  auto stA = [&](int d, int h, int kt){
    #pragma unroll
    for (int rd = 0; rd < 2; ++rd){
      int c = rd * 512 + tid, row = c >> 3, sl = c & 7;
      GLOAD_LDS16(A + (size_t)(m0 + h * 128 + row) * K + kt + ((sl ^ (row & 7)) * 8),
                  &Als[d][h][(rd * 512 + wid * 64) * 8]);
    }
  };
  auto stB = [&](int d, int h, int kt){
    #pragma unroll
    for (int rd = 0; rd < 2; ++rd){
      int c = rd * 512 + tid, row = c >> 3, sl = c & 7;
      GLOAD_LDS16(Bmat + (size_t)(n0 + h * 128 + row) * K + kt + ((sl ^ (row & 7)) * 8),
                  &Bls[d][h][(rd * 512 + wid * 64) * 8]);
    }
  };

  bf16x8 a_[4][2], b01[2][2], b23[2][2];

#define RDA(D, FIB)                                                            \
  { _Pragma("unroll") for (int fi = 0; fi < 4; ++fi)                           \
    _Pragma("unroll") for (int ks = 0; ks < 2; ++ks)                           \
      a_[fi][ks] = *reinterpret_cast<const bf16x8*>(                           \
        &Als[D][wr][((FIB) * 16 + fi * 16 + r16) * 64 +                        \
                    (((ks * 4 + g) ^ sx) * 8)]); }
#define RDB(D, BR, FJB)                                                        \
  { _Pragma("unroll") for (int fj = 0; fj < 2; ++fj)                           \
    _Pragma("unroll") for (int ks = 0; ks < 2; ++ks)                           \
      BR[fj][ks] = *reinterpret_cast<const bf16x8*>(                           \
        &Bls[D][(wc >> 1)][((wc & 1) * 64 + ((FJB) + fj) * 16 + r16) * 64 +    \
                           (((ks * 4 + g) ^ sx) * 8)]); }
#define MFMA16(AR, AC, BR)                                                     \
  { _Pragma("unroll") for (int fi = 0; fi < 4; ++fi)                           \
    _Pragma("unroll") for (int fj = 0; fj < 2; ++fj)                           \
    _Pragma("unroll") for (int ks = 0; ks < 2; ++ks)                           \
      acc[(AR) + fi][(AC) + fj] = __builtin_amdgcn_mfma_f32_16x16x32_bf16(     \
        a_[fi][ks], BR[fj][ks], acc[(AR) + fi][(AC) + fj], 0, 0, 0); }

  // prologue: tile0 full (8 loads) + tile1 A (4); retire tile0, keep tile1A
  stA(0, 0, 0);  stA(0, 1, 0);  stB(0, 0, 0);  stB(0, 1, 0);
  stA(1, 0, 64); stA(1, 1, 64);
  asm volatile("s_waitcnt vmcnt(4)" ::: "memory");
  BAR();

  for (int i = 0; i < NITER; ++i){
    const int ktb  = i * 128 + 64;           // tile 2i+1
    const int ktna = i * 128 + 128;          // tile 2i+2
    const int ktnb = i * 128 + 192;          // tile 2i+3
    const bool pf = (i + 1 < NITER);

    // ---- p0: buf0 A(fi0-3) + B(fj0-1); stage tbB ----
    RDA(0, 0); RDB(0, b01, 0);
    BAR();
    stB(1, 0, ktb); stB(1, 1, ktb);
    PRIO1(); MFMA16(0, 0, b01); PRIO0();
    BAR();
    // ---- p1: buf0 B(fj2-3) ----
    RDB(0, b23, 2);
    BAR();
    PRIO1(); MFMA16(0, 2, b23); PRIO0();
    BAR();
    // ---- p2: buf0 A(fi4-7) ----
    RDA(0, 4);
    BAR();
    PRIO1(); MFMA16(4, 2, b23); PRIO0();
    BAR();
    // ---- p3: regs only; stage naA; vmcnt covers tb (buf1) ----
    if (pf){ stA(0, 0, ktna); stA(0, 1, ktna); }
    PRIO1(); MFMA16(4, 0, b01); PRIO0();
    if (pf) asm volatile("s_waitcnt vmcnt(4)" ::: "memory");
    else    asm volatile("s_waitcnt vmcnt(0)" ::: "memory");
    BAR();
    // ---- p4: buf1 A(fi0-3) + B(fj0-1); stage naB ----
    RDA(1, 0); RDB(1, b01, 0);
    BAR();
    if (pf){ stB(0, 0, ktna); stB(0, 1, ktna); }
    PRIO1(); MFMA16(0, 0, b01); PRIO0();
    BAR();
    // ---- p5: buf1 B(fj2-3) ----
    RDB(1, b23, 2);
    BAR();
    PRIO1(); MFMA16(0, 2, b23); PRIO0();
    BAR();
    // ---- p6: buf1 A(fi4-7) ----
    RDA(1, 4);
    BAR();
    PRIO1(); MFMA16(4, 2, b23); PRIO0();
    BAR();
    // ---- p7: regs only; stage nbA; vmcnt covers na (buf0) ----
    if (pf){ stA(1, 0, ktnb); stA(1, 1, ktnb); }
    PRIO1(); MFMA16(4, 0, b01); PRIO0();
    if (pf) asm volatile("s_waitcnt vmcnt(4)" ::: "memory");
    BAR();
  }

  // epilogue; C layout: col = lane&15, row = (lane>>4)*4 + e
  #pragma unroll
  for (int fi = 0; fi < 8; ++fi){
    int row0 = m0 + wr*128 + fi*16 + g*4;
    int b2 = row0 >> 11, s0 = row0 & (S_ - 1);
    #pragma unroll
    for (int fj = 0; fj < 4; ++fj){
      int col = n0 + wc*64 + fj*16 + r16;
      int h2 = col >> 7, dd = col & 127;
      int bh = b2 * H_ + h2;
      if (which == 2){
        ushort4 pk;
        pk.x = f2bf(acc[fi][fj][0]); pk.y = f2bf(acc[fi][fj][1]);
        pk.z = f2bf(acc[fi][fj][2]); pk.w = f2bf(acc[fi][fj][3]);
        *reinterpret_cast<ushort4*>(&vtb[((size_t)bh * HD_ + dd) * S_ + s0]) = pk;
      } else {
        u16* dstb = (which == 0) ? qb : kb;
        #pragma unroll
        for (int e = 0; e < 4; ++e)
          dstb[((size_t)bh * S_ + s0 + e) * HD_ + dd] = f2bf(acc[fi][fj][e]);
      }
    }
  }
#undef RDA
#undef RDB
#undef MFMA16
}

// ---------------- 128x128 bf16 GEMM (O-projection), BK=32, 4 waves ----------------
template<int MODE>
__global__ __launch_bounds__(256) void gemm128_kernel(
    const u16* __restrict__ A,
    const u16* __restrict__ B0, const u16* __restrict__ B1, const u16* __restrict__ B2,
    u16* __restrict__ qb, u16* __restrict__ kb, u16* __restrict__ vtb,
    float* __restrict__ outp)
{
  constexpr int K = 2048;
  __shared__ u16 As[128 * 32];
  __shared__ u16 Bs[128 * 32];
  int m0 = blockIdx.x * 128;
  int by = blockIdx.y;
  int which, n0;
  const u16* Bmat;
  if (MODE == 0){ which = by >> 4; n0 = (by & 15) * 128;
                  Bmat = (which == 0) ? B0 : ((which == 1) ? B1 : B2); }
  else          { which = 0; n0 = by * 128; Bmat = B0; }

  int tid  = threadIdx.x;
  int lane = tid & 63;
  int wid  = tid >> 6;
  int wr = wid >> 1, wc = wid & 1;        // 2x2 waves -> 64x64 each
  int g = lane >> 4, r = lane & 15;

  f32x4 zero = {0.f, 0.f, 0.f, 0.f};
  f32x4 acc[4][4];
  #pragma unroll
  for (int i = 0; i < 4; ++i)
    #pragma unroll
    for (int j = 0; j < 4; ++j) acc[i][j] = zero;

  for (int kt = 0; kt < K; kt += 32){
    #pragma unroll
    for (int jj = 0; jj < 2; ++jj){
      int cbase = wid * 64 + jj * 256;          // wave-uniform LDS chunk base
      int c  = cbase + lane;
      int rr = c >> 2, c8 = c & 3;
      GLOAD_LDS16(&A[(size_t)(m0 + rr) * K + kt + c8 * 8],    &As[cbase * 8]);
      GLOAD_LDS16(&Bmat[(size_t)(n0 + rr) * K + kt + c8 * 8], &Bs[cbase * 8]);
    }
    asm volatile("s_waitcnt vmcnt(0)" ::: "memory");
    __syncthreads();
    bf16x8 af[4], bfr[4];
    #pragma unroll
    for (int i = 0; i < 4; ++i)
      af[i]  = *reinterpret_cast<bf16x8*>(&As[(wr*64 + i*16 + r) * 32 + g * 8]);
    #pragma unroll
    for (int i = 0; i < 4; ++i)
      bfr[i] = *reinterpret_cast<bf16x8*>(&Bs[(wc*64 + i*16 + r) * 32 + g * 8]);
    #pragma unroll
    for (int i = 0; i < 4; ++i)
      #pragma unroll
      for (int j = 0; j < 4; ++j)
        acc[i][j] = __builtin_amdgcn_mfma_f32_16x16x32_bf16(af[i], bfr[j], acc[i][j], 0, 0, 0);
    __syncthreads();
  }

  // epilogue; C layout: col = lane&15, row = (lane>>4)*4 + e
  #pragma unroll
  for (int i = 0; i < 4; ++i){
    int row0 = m0 + wr*64 + i*16 + g*4;
    int b  = row0 >> 11, s0 = row0 & (S_ - 1);
    #pragma unroll
    for (int j = 0; j < 4; ++j){
      int col = n0 + wc*64 + j*16 + r;
      if (MODE == 1){
        #pragma unroll
        for (int e = 0; e < 4; ++e)
          outp[(size_t)(row0 + e) * D_ + col] = acc[i][j][e];
      } else {
        int h = col >> 7, d = col & 127;
        int bh = b * H_ + h;
        if (which == 2){
          ushort4 pk;
          pk.x = f2bf(acc[i][j][0]); pk.y = f2bf(acc[i][j][1]);
          pk.z = f2bf(acc[i][j][2]); pk.w = f2bf(acc[i][j][3]);
          *reinterpret_cast<ushort4*>(&vtb[((size_t)bh * HD_ + d) * S_ + s0]) = pk;
        } else {
          u16* dstb = (which == 0) ? qb : kb;
          #pragma unroll
          for (int e = 0; e < 4; ++e)
            dstb[((size_t)bh * S_ + s0 + e) * HD_ + d] = f2bf(acc[i][j][e]);
        }
      }
    }
  }
}

// ---------------- RoPE in place on q/k [bh][s][128] ----------------
__global__ void rope_kernel(u16* __restrict__ qbuf, u16* __restrict__ kbuf){
  int idx = blockIdx.x * 256 + threadIdx.x;   // 32*2048*64 threads
  int j  = idx & 63;
  int s  = (idx >> 6) & (S_ - 1);
  int bh = idx >> 17;
  const float LOG2_1E4 = 13.287712379549449f;
  float inv = exp2f(-(float)(2 * j) * (LOG2_1E4 / 128.f));
  float ang = (float)s * inv;
  float sn = __sinf(ang), cs = __cosf(ang);
  size_t base = ((size_t)bh * S_ + s) * HD_;
  float x1 = bf2f(qbuf[base + j]), x2 = bf2f(qbuf[base + 64 + j]);
  qbuf[base + j]      = f2bf(x1 * cs - x2 * sn);
  qbuf[base + 64 + j] = f2bf(x2 * cs + x1 * sn);
  float y1 = bf2f(kbuf[base + j]), y2 = bf2f(kbuf[base + 64 + j]);
  kbuf[base + j]      = f2bf(y1 * cs - y2 * sn);
  kbuf[base + 64 + j] = f2bf(y2 * cs + y1 * sn);
}

// ---------------- attention v5: flash-style LDS-shared K/V, double-buffered ----------
__global__ __launch_bounds__(256) void attn5_kernel(
  const u16* __restrict__ qbuf, const u16* __restrict__ kbuf,
  const u16* __restrict__ vtb,  u16* __restrict__ ob)
{
  __shared__ u16 Klds[2][32 * 128];   // 8 KB per buffer
  __shared__ u16 Vlds[2][128 * 32];   // 8 KB per buffer

  const int lane = threadIdx.x & 63;
  const int wid  = threadIdx.x >> 6;     // 0..3 = q-chunk within block
  const int r    = lane & 31;
  const int hi   = lane >> 5;
  const int bh   = blockIdx.x;
  const int qblk = 15 - blockIdx.y;      // heavy blocks dispatched first
  const int qc   = qblk * 128 + wid * 32;
  const int cend = 4 * qblk + wid;       // this wave's diagonal kv tile
  const int tmax = 4 * qblk + 3;         // last tile staged by the block

  const float SCALE = 0.08838834764831845f;  // 1/sqrt(128)

  const size_t sbase = (size_t)bh * S_ * HD_;
  const size_t vbase = (size_t)bh * HD_ * S_;

  // Q fragments: lane holds Q[qc+r][d = cc*16 + hi*8 + j]
  bf16x8 qf[8];
  {
    const u16* qrow = qbuf + sbase + (size_t)(qc + r) * HD_ + hi * 8;
    #pragma unroll
    for (int cc = 0; cc < 8; ++cc)
      qf[cc] = *reinterpret_cast<const bf16x8*>(qrow + cc * 16);
  }

  f32x16 oacc[4];
  #pragma unroll
  for (int i = 0; i < 4; ++i)
    #pragma unroll
    for (int j = 0; j < 16; ++j) oacc[i][j] = 0.f;
  float lsum = 0.f;

  auto stage = [&](int buf, int t){
    const int kv0 = t * 32;
    u16* Kt = &Klds[buf][0];
    u16* Vt = &Vlds[buf][0];
    #pragma unroll
    for (int j = 0; j < 2; ++j){
      const int cbase = wid * 64 + j * 256;   // wave-uniform
      const int ck = cbase + lane;
      const int krow = ck >> 4, kslot = ck & 15;
      GLOAD_LDS16(kbuf + sbase + (size_t)(kv0 + krow) * HD_ + ((kslot ^ (krow & 15)) * 8),
                  Kt + cbase * 8);
      const int vd = ck >> 2, vslot = ck & 3;
      GLOAD_LDS16(vtb + vbase + (size_t)vd * S_ + kv0 + ((vslot ^ ((vd >> 1) & 3)) * 8),
                  Vt + cbase * 8);
    }
  };

  stage(0, 0);
  asm volatile("s_waitcnt vmcnt(0)" ::: "memory");
  __syncthreads();

  for (int t = 0; t <= tmax; ++t){
    const int cur = t & 1;
    if (t < tmax) stage(cur ^ 1, t + 1);

    if (t <= cend){
      const bool diag = (t == cend);
      f32x16 sc;
      #pragma unroll
      for (int j = 0; j < 16; ++j) sc[j] = 0.f;
      const u16* Kt = &Klds[cur][0];
      #pragma unroll
      for (int cc = 0; cc < 8; ++cc){
        const int slot = (cc * 2 + hi) ^ (r & 15);
        bf16x8 kf = *reinterpret_cast<const bf16x8*>(&Kt[r * 128 + slot * 8]);
        sc = __builtin_amdgcn_mfma_f32_32x32x16_bf16(kf, qf[cc], sc, 0, 0, 0);
      }
      float p[16];
      #pragma unroll
      for (int reg = 0; reg < 16; ++reg){
        float tt = sc[reg] * SCALE;
        float u  = tt * tt * 4.0e-4f;
        float capped = tt * (1.f - u * 0.33333333f + u * u * 0.13333333f);
        float pv = __expf(capped);
        if (diag){
          int kl = (reg & 3) + 8 * (reg >> 2) + 4 * hi;
          if (kl > r) pv = 0.f;
        }
        p[reg] = pv;
        lsum += pv;
      }
      unsigned a[4], b[4];
      #pragma unroll
      for (int r4 = 0; r4 < 4; ++r4){
        a[r4] = pack_bf16x2(p[r4*4+0], p[r4*4+1]);
        b[r4] = pack_bf16x2(p[r4*4+2], p[r4*4+3]);
      }
      unsigned ra0 = __shfl_xor(hi ? a[0] : a[1], 32);
      unsigned rb0 = __shfl_xor(hi ? b[0] : b[1], 32);
      unsigned ra1 = __shfl_xor(hi ? a[2] : a[3], 32);
      unsigned rb1 = __shfl_xor(hi ? b[2] : b[3], 32);
      unsigned pw[8];
      pw[0] = hi ? ra0 : a[0];  pw[1] = hi ? rb0 : b[0];
      pw[2] = hi ? a[1] : ra0;  pw[3] = hi ? b[1] : rb0;
      pw[4] = hi ? ra1 : a[2];  pw[5] = hi ? rb1 : b[2];
      pw[6] = hi ? a[3] : ra1;  pw[7] = hi ? b[3] : rb1;
      bf16x8 pb0, pb1;
      __builtin_memcpy(&pb0, &pw[0], 16);
      __builtin_memcpy(&pb1, &pw[4], 16);
      const u16* Vt = &Vlds[cur][0];
      #pragma unroll
      for (int i = 0; i < 4; ++i){
        const int d  = i * 32 + r;
        const int sw = (d >> 1) & 3;
        bf16x8 vf0 = *reinterpret_cast<const bf16x8*>(&Vt[d * 32 + (hi ^ sw) * 8]);
        oacc[i] = __builtin_amdgcn_mfma_f32_32x32x16_bf16(vf0, pb0, oacc[i], 0, 0, 0);
        bf16x8 vf1 = *reinterpret_cast<const bf16x8*>(&Vt[d * 32 + ((2 + hi) ^ sw) * 8]);
        oacc[i] = __builtin_amdgcn_mfma_f32_32x32x16_bf16(vf1, pb1, oacc[i], 0, 0, 0);
      }
    }
    asm volatile("s_waitcnt vmcnt(0)" ::: "memory");
    __syncthreads();
  }

  float lt = lsum + __shfl_xor(lsum, 32);
  float linv = 1.0f / (1.0f + lt);       // +1 = sink term exp(-m), m=0

  const int b = bh >> 4, h = bh & 15;
  u16* orow = ob + ((size_t)(b * S_ + qc + r)) * D_ + h * HD_;
  #pragma unroll
  for (int i = 0; i < 4; ++i){
    #pragma unroll
    for (int r4 = 0; r4 < 4; ++r4){
      ushort4 st;
      st.x = f2bf(oacc[i][r4*4+0] * linv);
      st.y = f2bf(oacc[i][r4*4+1] * linv);
      st.z = f2bf(oacc[i][r4*4+2] * linv);
      st.w = f2bf(oacc[i][r4*4+3] * linv);
      *reinterpret_cast<ushort4*>(orow + i*32 + r4*8 + hi*4) = st;
    }
  }
}

extern "C" void kernel_launch(void* const* d_in, const int* in_sizes, int n_in,
                              void* d_out, int out_size, void* d_ws, size_t ws_size,
                              hipStream_t stream){
  const float* x  = (const float*)d_in[0];
  const float* Wq = (const float*)d_in[1];
  const float* Wk = (const float*)d_in[2];
  const float* Wv = (const float*)d_in[3];
  const float* Wo = (const float*)d_in[4];
  float* out = (float*)d_out;
  char* ws = (char*)d_ws;

  // workspace layout (112 MB total)
  u16* xb   = (u16*)(ws);                      // 16 MB  x bf16 [4096][2048]
  u16* wtq  = (u16*)(ws + (size_t)(16u << 20));//  8 MB  Wq^T bf16 [N][K]
  u16* wtk  = (u16*)(ws + (size_t)(24u << 20));
  u16* wtv  = (u16*)(ws + (size_t)(32u << 20));
  u16* wto  = (u16*)(ws + (size_t)(40u << 20));
  u16* qbuf = (u16*)(ws + (size_t)(48u << 20));// 16 MB  [bh][s][128]
  u16* kbuf = (u16*)(ws + (size_t)(64u << 20));// 16 MB  [bh][s][128]
  u16* vtb  = (u16*)(ws + (size_t)(80u << 20));// 16 MB  [bh][128][s]
  u16* atb  = (u16*)(ws + (size_t)(96u << 20));// 16 MB  [b*S+s][h*128+d]

  cast_x_kernel<<<8192, 256, 0, stream>>>(x, xb);
  wtrans_kernel<<<dim3(64, 64, 4), 256, 0, stream>>>(Wq, Wk, Wv, Wo, wtq, wtk, wtv, wto);
  gemm256p8_kernel<<<384, 512, 0, stream>>>(xb, wtq, wtk, wtv, qbuf, kbuf, vtb);
  rope_kernel<<<16384, 256, 0, stream>>>(qbuf, kbuf);
  attn5_kernel<<<dim3(32, 16), 256, 0, stream>>>(qbuf, kbuf, vtb, atb);
  gemm128_kernel<1><<<dim3(32, 16), 256, 0, stream>>>(atb, wto, nullptr, nullptr,
                                                      nullptr, nullptr, nullptr, out);
}

// Round 9
// 292.336 us; speedup vs baseline: 1.1798x; 1.1172x over previous
//
#include <hip/hip_runtime.h>
#include <hip/hip_bf16.h>

// Problem: B=2, S=2048, D=2048, H=16, HD=128
#define B_  2
#define S_  2048
#define D_  2048
#define H_  16
#define HD_ 128

typedef unsigned short u16;
typedef __attribute__((ext_vector_type(8))) short bf16x8;
typedef __attribute__((ext_vector_type(4))) float f32x4;
typedef __attribute__((ext_vector_type(16))) float f32x16;

#define GLOAD_LDS16(g, l)                                                     \
  __builtin_amdgcn_global_load_lds(                                           \
      (const __attribute__((address_space(1))) void*)(g),                     \
      (__attribute__((address_space(3))) void*)(l), 16, 0, 0)

__device__ __forceinline__ u16 f2bf(float f){
  unsigned u; __builtin_memcpy(&u, &f, 4);
  u += 0x7fffu + ((u >> 16) & 1u);     // round-to-nearest-even
  return (u16)(u >> 16);
}
__device__ __forceinline__ float bf2f(u16 h){
  unsigned u = ((unsigned)h) << 16; float f; __builtin_memcpy(&f, &u, 4); return f;
}
__device__ __forceinline__ unsigned pack_bf16x2(float lo, float hi){
  __hip_bfloat162 h2 = __float22bfloat162_rn(float2{lo, hi});  // v_cvt_pk_bf16_f32
  unsigned u; __builtin_memcpy(&u, &h2, 4); return u;
}

// ---------------- cast x (fp32 -> bf16) ----------------
__global__ void cast_x_kernel(const float* __restrict__ x, u16* __restrict__ xb){
  int i = blockIdx.x * 256 + threadIdx.x;            // 2,097,152 float4s
  float4 v = reinterpret_cast<const float4*>(x)[i];
  ushort4 o; o.x = f2bf(v.x); o.y = f2bf(v.y); o.z = f2bf(v.z); o.w = f2bf(v.w);
  reinterpret_cast<ushort4*>(xb)[i] = o;
}

// ---------------- transpose + cast weights: Wt[n][k] = W[k][n] ----------------
__global__ void wtrans_kernel(const float* __restrict__ w0, const float* __restrict__ w1,
                              const float* __restrict__ w2, const float* __restrict__ w3,
                              u16* __restrict__ o0, u16* __restrict__ o1,
                              u16* __restrict__ o2, u16* __restrict__ o3){
  __shared__ float t[32][33];
  const float* src; u16* dst;
  switch (blockIdx.z){
    case 0:  src = w0; dst = o0; break;
    case 1:  src = w1; dst = o1; break;
    case 2:  src = w2; dst = o2; break;
    default: src = w3; dst = o3; break;
  }
  int j0 = blockIdx.x * 32, i0 = blockIdx.y * 32;
  int tx = threadIdx.x & 31, ty = threadIdx.x >> 5;   // 256 thr: 32 x 8
  #pragma unroll
  for (int rr = 0; rr < 4; ++rr)
    t[ty + rr*8][tx] = src[(size_t)(i0 + ty + rr*8) * D_ + j0 + tx];
  __syncthreads();
  #pragma unroll
  for (int rr = 0; rr < 4; ++rr)
    dst[(size_t)(j0 + ty + rr*8) * D_ + i0 + tx] = f2bf(t[tx][ty + rr*8]);
}

// ---------------- 128x128 bf16 GEMM, BK=32, 4 waves, 16x16x32 MFMA ----------------
// 1D grid + XCD-bijective swizzle: xcd = bid&7 owns a contiguous slice of n-panels
// walked m-fastest (B-panel stays hot in that XCD's L2).
// MODE 0: QKV (1536 blocks: 32 m x 48 n), scatter epilogue. MODE 1: O (512: 32 x 16).
template<int MODE>
__global__ __launch_bounds__(256) void gemm128_kernel(
    const u16* __restrict__ A,
    const u16* __restrict__ B0, const u16* __restrict__ B1, const u16* __restrict__ B2,
    u16* __restrict__ qb, u16* __restrict__ kb, u16* __restrict__ vtb,
    float* __restrict__ outp)
{
  constexpr int K = 2048;
  __shared__ u16 As[128 * 32];
  __shared__ u16 Bs[128 * 32];
  const int bid = blockIdx.x;
  const int xcd = bid & 7, loc = bid >> 3;
  const int mq  = loc & 31;                 // m fastest within XCD slice
  const int nl  = loc >> 5;                 // 0..5 (MODE0) | 0..1 (MODE1)
  const int by  = (MODE == 0) ? (xcd * 6 + nl) : (xcd * 2 + nl);
  const int m0  = mq * 128;
  int which, n0;
  const u16* Bmat;
  if (MODE == 0){ which = by >> 4; n0 = (by & 15) * 128;
                  Bmat = (which == 0) ? B0 : ((which == 1) ? B1 : B2); }
  else          { which = 0; n0 = by * 128; Bmat = B0; }

  int tid  = threadIdx.x;
  int lane = tid & 63;
  int wid  = tid >> 6;
  int wr = wid >> 1, wc = wid & 1;        // 2x2 waves -> 64x64 each
  int g = lane >> 4, r = lane & 15;

  f32x4 zero = {0.f, 0.f, 0.f, 0.f};
  f32x4 acc[4][4];
  #pragma unroll
  for (int i = 0; i < 4; ++i)
    #pragma unroll
    for (int j = 0; j < 4; ++j) acc[i][j] = zero;

  for (int kt = 0; kt < K; kt += 32){
    #pragma unroll
    for (int jj = 0; jj < 2; ++jj){
      int cbase = wid * 64 + jj * 256;          // wave-uniform LDS chunk base
      int c  = cbase + lane;
      int rr = c >> 2, c8 = c & 3;
      GLOAD_LDS16(&A[(size_t)(m0 + rr) * K + kt + c8 * 8],    &As[cbase * 8]);
      GLOAD_LDS16(&Bmat[(size_t)(n0 + rr) * K + kt + c8 * 8], &Bs[cbase * 8]);
    }
    asm volatile("s_waitcnt vmcnt(0)" ::: "memory");
    __syncthreads();
    bf16x8 af[4], bfr[4];
    #pragma unroll
    for (int i = 0; i < 4; ++i)
      af[i]  = *reinterpret_cast<bf16x8*>(&As[(wr*64 + i*16 + r) * 32 + g * 8]);
    #pragma unroll
    for (int i = 0; i < 4; ++i)
      bfr[i] = *reinterpret_cast<bf16x8*>(&Bs[(wc*64 + i*16 + r) * 32 + g * 8]);
    #pragma unroll
    for (int i = 0; i < 4; ++i)
      #pragma unroll
      for (int j = 0; j < 4; ++j)
        acc[i][j] = __builtin_amdgcn_mfma_f32_16x16x32_bf16(af[i], bfr[j], acc[i][j], 0, 0, 0);
    __syncthreads();
  }

  // epilogue; C layout: col = lane&15, row = (lane>>4)*4 + e
  #pragma unroll
  for (int i = 0; i < 4; ++i){
    int row0 = m0 + wr*64 + i*16 + g*4;
    int b  = row0 >> 11, s0 = row0 & (S_ - 1);
    #pragma unroll
    for (int j = 0; j < 4; ++j){
      int col = n0 + wc*64 + j*16 + r;
      if (MODE == 1){
        #pragma unroll
        for (int e = 0; e < 4; ++e)
          outp[(size_t)(row0 + e) * D_ + col] = acc[i][j][e];
      } else {
        int h = col >> 7, d = col & 127;
        int bh = b * H_ + h;
        if (which == 2){
          ushort4 pk;
          pk.x = f2bf(acc[i][j][0]); pk.y = f2bf(acc[i][j][1]);
          pk.z = f2bf(acc[i][j][2]); pk.w = f2bf(acc[i][j][3]);
          *reinterpret_cast<ushort4*>(&vtb[((size_t)bh * HD_ + d) * S_ + s0]) = pk;
        } else {
          u16* dstb = (which == 0) ? qb : kb;
          #pragma unroll
          for (int e = 0; e < 4; ++e)
            dstb[((size_t)bh * S_ + s0 + e) * HD_ + d] = f2bf(acc[i][j][e]);
        }
      }
    }
  }
}

// ---------------- RoPE in place on q/k [bh][s][128] ----------------
__global__ void rope_kernel(u16* __restrict__ qbuf, u16* __restrict__ kbuf){
  int idx = blockIdx.x * 256 + threadIdx.x;   // 32*2048*64 threads
  int j  = idx & 63;
  int s  = (idx >> 6) & (S_ - 1);
  int bh = idx >> 17;
  const float LOG2_1E4 = 13.287712379549449f;
  float inv = exp2f(-(float)(2 * j) * (LOG2_1E4 / 128.f));
  float ang = (float)s * inv;
  float sn = __sinf(ang), cs = __cosf(ang);
  size_t base = ((size_t)bh * S_ + s) * HD_;
  float x1 = bf2f(qbuf[base + j]), x2 = bf2f(qbuf[base + 64 + j]);
  qbuf[base + j]      = f2bf(x1 * cs - x2 * sn);
  qbuf[base + 64 + j] = f2bf(x2 * cs + x1 * sn);
  float y1 = bf2f(kbuf[base + j]), y2 = bf2f(kbuf[base + 64 + j]);
  kbuf[base + j]      = f2bf(y1 * cs - y2 * sn);
  kbuf[base + 64 + j] = f2bf(y2 * cs + y1 * sn);
}

// ---------------- attention v6: flash LDS K/V, KVBLK=64, double-buffered ----------
// Block = 4 waves x 32 q rows. Per 64-key tile: K[64][128] (slot^=row&15) and
// V^T[128][64] (slot^=d&7) staged via global_load_lds (linear dest, pre-swizzled
// global source; read side applies the same XOR). One vmcnt(0)+barrier per 64 keys
// (halved vs KVBLK=32). Grid 512 = exactly 2 blocks/CU (64KB LDS), zero tail.
// m=0 softmax (scores capped +-50 -> exp bounded; partials exact); poly tanh-cap.
__global__ __launch_bounds__(256) void attn6_kernel(
  const u16* __restrict__ qbuf, const u16* __restrict__ kbuf,
  const u16* __restrict__ vtb,  u16* __restrict__ ob)
{
  __shared__ u16 Klds[2][64 * 128];   // 16 KB per buffer
  __shared__ u16 Vlds[2][128 * 64];   // 16 KB per buffer

  const int lane = threadIdx.x & 63;
  const int wid  = threadIdx.x >> 6;     // 0..3 = q-chunk within block
  const int r    = lane & 31;
  const int hi   = lane >> 5;
  const int bh   = blockIdx.x;
  const int qblk = 15 - blockIdx.y;      // heavy blocks dispatched first
  const int qc   = qblk * 128 + wid * 32;
  const int qc32 = qc >> 5;              // diagonal 32-subtile index
  const int T    = 2 * qblk + 2;         // 64-key tiles staged by the block

  const float SCALE = 0.08838834764831845f;  // 1/sqrt(128)

  const size_t sbase = (size_t)bh * S_ * HD_;
  const size_t vbase = (size_t)bh * HD_ * S_;

  // Q fragments: lane holds Q[qc+r][d = cc*16 + hi*8 + j]
  bf16x8 qf[8];
  {
    const u16* qrow = qbuf + sbase + (size_t)(qc + r) * HD_ + hi * 8;
    #pragma unroll
    for (int cc = 0; cc < 8; ++cc)
      qf[cc] = *reinterpret_cast<const bf16x8*>(qrow + cc * 16);
  }

  f32x16 oacc[4];
  #pragma unroll
  for (int i = 0; i < 4; ++i)
    #pragma unroll
    for (int j = 0; j < 16; ++j) oacc[i][j] = 0.f;
  float lsum = 0.f;

  // stage 64-key tile t: K 16KB (1024 chunks) + V 16KB; 8 gload_lds/thread
  auto stage = [&](int buf, int t){
    const int kv0 = t * 64;
    u16* Kt = &Klds[buf][0];
    u16* Vt = &Vlds[buf][0];
    #pragma unroll
    for (int j = 0; j < 4; ++j){
      const int cbase = j * 256 + wid * 64;   // wave-uniform
      const int ck = cbase + lane;
      const int krow = ck >> 4, kslot = ck & 15;
      GLOAD_LDS16(kbuf + sbase + (size_t)(kv0 + krow) * HD_ + ((kslot ^ (krow & 15)) * 8),
                  Kt + cbase * 8);
      const int vd = ck >> 3, vslot = ck & 7;
      GLOAD_LDS16(vtb + vbase + (size_t)vd * S_ + kv0 + ((vslot ^ (vd & 7)) * 8),
                  Vt + cbase * 8);
    }
  };

  stage(0, 0);
  asm volatile("s_waitcnt vmcnt(0)" ::: "memory");
  __syncthreads();

  for (int t = 0; t < T; ++t){
    const int cur = t & 1;
    if (t + 1 < T) stage(cur ^ 1, t + 1);

    const u16* Kt = &Klds[cur][0];
    const u16* Vt = &Vlds[cur][0];
    #pragma unroll
    for (int sub = 0; sub < 2; ++sub){
      const int t32 = 2 * t + sub;
      if (t32 <= qc32){
        const bool diag = (t32 == qc32);
        // QK^T (swapped): lane holds 16 scores for q col = r
        f32x16 sc;
        #pragma unroll
        for (int j = 0; j < 16; ++j) sc[j] = 0.f;
        #pragma unroll
        for (int cc = 0; cc < 8; ++cc){
          const int row = sub * 32 + r;
          const int slot = (cc * 2 + hi) ^ (r & 15);
          bf16x8 kf = *reinterpret_cast<const bf16x8*>(&Kt[row * 128 + slot * 8]);
          sc = __builtin_amdgcn_mfma_f32_32x32x16_bf16(kf, qf[cc], sc, 0, 0, 0);
        }
        // 50*tanh(x/50) = x*(1 - u/3 + 2u^2/15), u=(x/50)^2 ; then exp
        float p[16];
        #pragma unroll
        for (int reg = 0; reg < 16; ++reg){
          float tt = sc[reg] * SCALE;
          float u  = tt * tt * 4.0e-4f;
          float capped = tt * (1.f - u * 0.33333333f + u * u * 0.13333333f);
          float pv = __expf(capped);
          if (diag){
            int kl = (reg & 3) + 8 * (reg >> 2) + 4 * hi;
            if (kl > r) pv = 0.f;
          }
          p[reg] = pv;
          lsum += pv;
        }
        // pack P to bf16; exchange quads across lane^32 -> PV B-fragments
        unsigned a[4], b[4];
        #pragma unroll
        for (int r4 = 0; r4 < 4; ++r4){
          a[r4] = pack_bf16x2(p[r4*4+0], p[r4*4+1]);
          b[r4] = pack_bf16x2(p[r4*4+2], p[r4*4+3]);
        }
        unsigned ra0 = __shfl_xor(hi ? a[0] : a[1], 32);
        unsigned rb0 = __shfl_xor(hi ? b[0] : b[1], 32);
        unsigned ra1 = __shfl_xor(hi ? a[2] : a[3], 32);
        unsigned rb1 = __shfl_xor(hi ? b[2] : b[3], 32);
        unsigned pw[8];
        pw[0] = hi ? ra0 : a[0];  pw[1] = hi ? rb0 : b[0];
        pw[2] = hi ? a[1] : ra0;  pw[3] = hi ? b[1] : rb0;
        pw[4] = hi ? ra1 : a[2];  pw[5] = hi ? rb1 : b[2];
        pw[6] = hi ? a[3] : ra1;  pw[7] = hi ? b[3] : rb1;
        bf16x8 pb0, pb1;
        __builtin_memcpy(&pb0, &pw[0], 16);
        __builtin_memcpy(&pb1, &pw[4], 16);
        // PV: O^T += V^T . P   (V slots: sub*4+hi, sub*4+2+hi; ^ (d&7))
        #pragma unroll
        for (int i = 0; i < 4; ++i){
          const int d  = i * 32 + r;
          const int sw = d & 7;
          bf16x8 vf0 = *reinterpret_cast<const bf16x8*>(
              &Vt[d * 64 + (((sub * 4 + hi) ^ sw) * 8)]);
          oacc[i] = __builtin_amdgcn_mfma_f32_32x32x16_bf16(vf0, pb0, oacc[i], 0, 0, 0);
          bf16x8 vf1 = *reinterpret_cast<const bf16x8*>(
              &Vt[d * 64 + (((sub * 4 + 2 + hi) ^ sw) * 8)]);
          oacc[i] = __builtin_amdgcn_mfma_f32_32x32x16_bf16(vf1, pb1, oacc[i], 0, 0, 0);
        }
      }
    }
    asm volatile("s_waitcnt vmcnt(0)" ::: "memory");
    __syncthreads();
  }

  float lt = lsum + __shfl_xor(lsum, 32);
  float linv = 1.0f / (1.0f + lt);       // +1 = sink term exp(-m), m=0

  // write: row q = qc+r, dv = i*32 + r4*8 + hi*4 + (0..3)
  const int b = bh >> 4, h = bh & 15;
  u16* orow = ob + ((size_t)(b * S_ + qc + r)) * D_ + h * HD_;
  #pragma unroll
  for (int i = 0; i < 4; ++i){
    #pragma unroll
    for (int r4 = 0; r4 < 4; ++r4){
      ushort4 st;
      st.x = f2bf(oacc[i][r4*4+0] * linv);
      st.y = f2bf(oacc[i][r4*4+1] * linv);
      st.z = f2bf(oacc[i][r4*4+2] * linv);
      st.w = f2bf(oacc[i][r4*4+3] * linv);
      *reinterpret_cast<ushort4*>(orow + i*32 + r4*8 + hi*4) = st;
    }
  }
}

extern "C" void kernel_launch(void* const* d_in, const int* in_sizes, int n_in,
                              void* d_out, int out_size, void* d_ws, size_t ws_size,
                              hipStream_t stream){
  const float* x  = (const float*)d_in[0];
  const float* Wq = (const float*)d_in[1];
  const float* Wk = (const float*)d_in[2];
  const float* Wv = (const float*)d_in[3];
  const float* Wo = (const float*)d_in[4];
  float* out = (float*)d_out;
  char* ws = (char*)d_ws;

  // workspace layout (112 MB total)
  u16* xb   = (u16*)(ws);                      // 16 MB  x bf16 [4096][2048]
  u16* wtq  = (u16*)(ws + (size_t)(16u << 20));//  8 MB  Wq^T bf16 [N][K]
  u16* wtk  = (u16*)(ws + (size_t)(24u << 20));
  u16* wtv  = (u16*)(ws + (size_t)(32u << 20));
  u16* wto  = (u16*)(ws + (size_t)(40u << 20));
  u16* qbuf = (u16*)(ws + (size_t)(48u << 20));// 16 MB  [bh][s][128]
  u16* kbuf = (u16*)(ws + (size_t)(64u << 20));// 16 MB  [bh][s][128]
  u16* vtb  = (u16*)(ws + (size_t)(80u << 20));// 16 MB  [bh][128][s]
  u16* atb  = (u16*)(ws + (size_t)(96u << 20));// 16 MB  [b*S+s][h*128+d]

  cast_x_kernel<<<8192, 256, 0, stream>>>(x, xb);
  wtrans_kernel<<<dim3(64, 64, 4), 256, 0, stream>>>(Wq, Wk, Wv, Wo, wtq, wtk, wtv, wto);
  gemm128_kernel<0><<<1536, 256, 0, stream>>>(xb, wtq, wtk, wtv,
                                              qbuf, kbuf, vtb, nullptr);
  rope_kernel<<<16384, 256, 0, stream>>>(qbuf, kbuf);
  // grid: bh fastest -> all 16 blocks of a bh land on XCD bh%8
  attn6_kernel<<<dim3(32, 16), 256, 0, stream>>>(qbuf, kbuf, vtb, atb);
  gemm128_kernel<1><<<512, 256, 0, stream>>>(atb, wto, nullptr, nullptr,
                                             nullptr, nullptr, nullptr, out);
}

// Round 10
// 274.674 us; speedup vs baseline: 1.2557x; 1.0643x over previous
//
#include <hip/hip_runtime.h>
#include <hip/hip_bf16.h>

// Problem: B=2, S=2048, D=2048, H=16, HD=128
#define B_  2
#define S_  2048
#define D_  2048
#define H_  16
#define HD_ 128

typedef unsigned short u16;
typedef __attribute__((ext_vector_type(8))) short bf16x8;
typedef __attribute__((ext_vector_type(4))) float f32x4;
typedef __attribute__((ext_vector_type(16))) float f32x16;

#define GLOAD_LDS16(g, l)                                                     \
  __builtin_amdgcn_global_load_lds(                                           \
      (const __attribute__((address_space(1))) void*)(g),                     \
      (__attribute__((address_space(3))) void*)(l), 16, 0, 0)

__device__ __forceinline__ u16 f2bf(float f){
  unsigned u; __builtin_memcpy(&u, &f, 4);
  u += 0x7fffu + ((u >> 16) & 1u);     // round-to-nearest-even
  return (u16)(u >> 16);
}
__device__ __forceinline__ float bf2f(u16 h){
  unsigned u = ((unsigned)h) << 16; float f; __builtin_memcpy(&f, &u, 4); return f;
}
__device__ __forceinline__ unsigned pack_bf16x2(float lo, float hi){
  __hip_bfloat162 h2 = __float22bfloat162_rn(float2{lo, hi});  // v_cvt_pk_bf16_f32
  unsigned u; __builtin_memcpy(&u, &h2, 4); return u;
}

// ---------------- cast x (fp32 -> bf16) ----------------
__global__ void cast_x_kernel(const float* __restrict__ x, u16* __restrict__ xb){
  int i = blockIdx.x * 256 + threadIdx.x;            // 2,097,152 float4s
  float4 v = reinterpret_cast<const float4*>(x)[i];
  ushort4 o; o.x = f2bf(v.x); o.y = f2bf(v.y); o.z = f2bf(v.z); o.w = f2bf(v.w);
  reinterpret_cast<ushort4*>(xb)[i] = o;
}

// ---------------- transpose + cast weights: Wt[n][k] = W[k][n] ----------------
__global__ void wtrans_kernel(const float* __restrict__ w0, const float* __restrict__ w1,
                              const float* __restrict__ w2, const float* __restrict__ w3,
                              u16* __restrict__ o0, u16* __restrict__ o1,
                              u16* __restrict__ o2, u16* __restrict__ o3){
  __shared__ float t[32][33];
  const float* src; u16* dst;
  switch (blockIdx.z){
    case 0:  src = w0; dst = o0; break;
    case 1:  src = w1; dst = o1; break;
    case 2:  src = w2; dst = o2; break;
    default: src = w3; dst = o3; break;
  }
  int j0 = blockIdx.x * 32, i0 = blockIdx.y * 32;
  int tx = threadIdx.x & 31, ty = threadIdx.x >> 5;   // 256 thr: 32 x 8
  #pragma unroll
  for (int rr = 0; rr < 4; ++rr)
    t[ty + rr*8][tx] = src[(size_t)(i0 + ty + rr*8) * D_ + j0 + tx];
  __syncthreads();
  #pragma unroll
  for (int rr = 0; rr < 4; ++rr)
    dst[(size_t)(j0 + ty + rr*8) * D_ + i0 + tx] = f2bf(t[tx][ty + rr*8]);
}

// ---------------- 128x128 bf16 GEMM, BK=64, 4 waves, 16x16x32 MFMA ----------------
// LDS [128][64] u16 (128B rows) + 16B-slot XOR swizzle slot^=(row&7) on BOTH the
// pre-swizzled global_load_lds source (linear dest) and the ds_read side
// (R7-measured: 0 bank conflicts). BK=64 halves the vmcnt(0)+barrier count vs BK=32.
// Grid 2D, m-tile fastest (XCD = m%8 -> A-slice L2-resident; R5-measured best).
// MODE 0: QKV fused over grid.y (48 n-tiles), scatter epilogue. MODE 1: O, fp32 out.
template<int MODE>
__global__ __launch_bounds__(256) void gemm128_kernel(
    const u16* __restrict__ A,
    const u16* __restrict__ B0, const u16* __restrict__ B1, const u16* __restrict__ B2,
    u16* __restrict__ qb, u16* __restrict__ kb, u16* __restrict__ vtb,
    float* __restrict__ outp)
{
  constexpr int K = 2048;
  __shared__ u16 As[128 * 64];   // 16 KB
  __shared__ u16 Bs[128 * 64];   // 16 KB
  int m0 = blockIdx.x * 128;
  int by = blockIdx.y;
  int which, n0;
  const u16* Bmat;
  if (MODE == 0){ which = by >> 4; n0 = (by & 15) * 128;
                  Bmat = (which == 0) ? B0 : ((which == 1) ? B1 : B2); }
  else          { which = 0; n0 = by * 128; Bmat = B0; }

  int tid  = threadIdx.x;
  int lane = tid & 63;
  int wid  = tid >> 6;
  int wr = wid >> 1, wc = wid & 1;        // 2x2 waves -> 64x64 each
  int g = lane >> 4, r = lane & 15;
  const int sx = r & 7;

  f32x4 zero = {0.f, 0.f, 0.f, 0.f};
  f32x4 acc[4][4];
  #pragma unroll
  for (int i = 0; i < 4; ++i)
    #pragma unroll
    for (int j = 0; j < 4; ++j) acc[i][j] = zero;

  for (int kt = 0; kt < K; kt += 64){
    // stage A,B 128x64 tiles (16 KB each): 1024 chunks, 4 per thread per matrix
    #pragma unroll
    for (int j = 0; j < 4; ++j){
      int cbase = j * 256 + wid * 64;           // wave-uniform LDS chunk base
      int c  = cbase + lane;
      int row = c >> 3, sl = c & 7;
      GLOAD_LDS16(&A[(size_t)(m0 + row) * K + kt + ((sl ^ (row & 7)) * 8)],
                  &As[cbase * 8]);
      GLOAD_LDS16(&Bmat[(size_t)(n0 + row) * K + kt + ((sl ^ (row & 7)) * 8)],
                  &Bs[cbase * 8]);
    }
    asm volatile("s_waitcnt vmcnt(0)" ::: "memory");
    __syncthreads();
    #pragma unroll
    for (int kk = 0; kk < 2; ++kk){
      bf16x8 af[4], bfr[4];
      #pragma unroll
      for (int i = 0; i < 4; ++i)
        af[i]  = *reinterpret_cast<bf16x8*>(
            &As[(wr*64 + i*16 + r) * 64 + (((kk*4 + g) ^ sx) * 8)]);
      #pragma unroll
      for (int i = 0; i < 4; ++i)
        bfr[i] = *reinterpret_cast<bf16x8*>(
            &Bs[(wc*64 + i*16 + r) * 64 + (((kk*4 + g) ^ sx) * 8)]);
      #pragma unroll
      for (int i = 0; i < 4; ++i)
        #pragma unroll
        for (int j = 0; j < 4; ++j)
          acc[i][j] = __builtin_amdgcn_mfma_f32_16x16x32_bf16(af[i], bfr[j], acc[i][j], 0, 0, 0);
    }
    __syncthreads();
  }

  // epilogue; C layout: col = lane&15, row = (lane>>4)*4 + e
  #pragma unroll
  for (int i = 0; i < 4; ++i){
    int row0 = m0 + wr*64 + i*16 + g*4;
    int b  = row0 >> 11, s0 = row0 & (S_ - 1);
    #pragma unroll
    for (int j = 0; j < 4; ++j){
      int col = n0 + wc*64 + j*16 + r;
      if (MODE == 1){
        #pragma unroll
        for (int e = 0; e < 4; ++e)
          outp[(size_t)(row0 + e) * D_ + col] = acc[i][j][e];
      } else {
        int h = col >> 7, d = col & 127;
        int bh = b * H_ + h;
        if (which == 2){
          ushort4 pk;
          pk.x = f2bf(acc[i][j][0]); pk.y = f2bf(acc[i][j][1]);
          pk.z = f2bf(acc[i][j][2]); pk.w = f2bf(acc[i][j][3]);
          *reinterpret_cast<ushort4*>(&vtb[((size_t)bh * HD_ + d) * S_ + s0]) = pk;
        } else {
          u16* dstb = (which == 0) ? qb : kb;
          #pragma unroll
          for (int e = 0; e < 4; ++e)
            dstb[((size_t)bh * S_ + s0 + e) * HD_ + d] = f2bf(acc[i][j][e]);
        }
      }
    }
  }
}

// ---------------- RoPE in place on q/k [bh][s][128] ----------------
__global__ void rope_kernel(u16* __restrict__ qbuf, u16* __restrict__ kbuf){
  int idx = blockIdx.x * 256 + threadIdx.x;   // 32*2048*64 threads
  int j  = idx & 63;
  int s  = (idx >> 6) & (S_ - 1);
  int bh = idx >> 17;
  const float LOG2_1E4 = 13.287712379549449f;
  float inv = exp2f(-(float)(2 * j) * (LOG2_1E4 / 128.f));
  float ang = (float)s * inv;
  float sn = __sinf(ang), cs = __cosf(ang);
  size_t base = ((size_t)bh * S_ + s) * HD_;
  float x1 = bf2f(qbuf[base + j]), x2 = bf2f(qbuf[base + 64 + j]);
  qbuf[base + j]      = f2bf(x1 * cs - x2 * sn);
  qbuf[base + 64 + j] = f2bf(x2 * cs + x1 * sn);
  float y1 = bf2f(kbuf[base + j]), y2 = bf2f(kbuf[base + 64 + j]);
  kbuf[base + j]      = f2bf(y1 * cs - y2 * sn);
  kbuf[base + 64 + j] = f2bf(y2 * cs + y1 * sn);
}

// ---------------- attention v6: flash LDS K/V, KVBLK=64, double-buffered ----------
// exp2-domain softmax: p = 2^y, y = tt2*(1 - u/3 + 2u^2/15), tt2 = s*SCALE*log2e,
// u = (s*SCALE/50)^2 = tt2^2*C2  -> 5 VALU + v_exp per score (was ~8).
__global__ __launch_bounds__(256) void attn6_kernel(
  const u16* __restrict__ qbuf, const u16* __restrict__ kbuf,
  const u16* __restrict__ vtb,  u16* __restrict__ ob)
{
  __shared__ u16 Klds[2][64 * 128];   // 16 KB per buffer
  __shared__ u16 Vlds[2][128 * 64];   // 16 KB per buffer

  const int lane = threadIdx.x & 63;
  const int wid  = threadIdx.x >> 6;     // 0..3 = q-chunk within block
  const int r    = lane & 31;
  const int hi   = lane >> 5;
  const int bh   = blockIdx.x;
  const int qblk = 15 - blockIdx.y;      // heavy blocks dispatched first
  const int qc   = qblk * 128 + wid * 32;
  const int qc32 = qc >> 5;              // diagonal 32-subtile index
  const int T    = 2 * qblk + 2;         // 64-key tiles staged by the block

  const float C1 = 0.12751757f;          // (1/sqrt(128)) * log2(e)
  const float C2 = 1.9218114e-4f;        // (ln2/50)^2

  const size_t sbase = (size_t)bh * S_ * HD_;
  const size_t vbase = (size_t)bh * HD_ * S_;

  // Q fragments: lane holds Q[qc+r][d = cc*16 + hi*8 + j]
  bf16x8 qf[8];
  {
    const u16* qrow = qbuf + sbase + (size_t)(qc + r) * HD_ + hi * 8;
    #pragma unroll
    for (int cc = 0; cc < 8; ++cc)
      qf[cc] = *reinterpret_cast<const bf16x8*>(qrow + cc * 16);
  }

  f32x16 oacc[4];
  #pragma unroll
  for (int i = 0; i < 4; ++i)
    #pragma unroll
    for (int j = 0; j < 16; ++j) oacc[i][j] = 0.f;
  float lsum = 0.f;

  // stage 64-key tile t: K 16KB + V 16KB; 8 gload_lds/thread
  auto stage = [&](int buf, int t){
    const int kv0 = t * 64;
    u16* Kt = &Klds[buf][0];
    u16* Vt = &Vlds[buf][0];
    #pragma unroll
    for (int j = 0; j < 4; ++j){
      const int cbase = j * 256 + wid * 64;   // wave-uniform
      const int ck = cbase + lane;
      const int krow = ck >> 4, kslot = ck & 15;
      GLOAD_LDS16(kbuf + sbase + (size_t)(kv0 + krow) * HD_ + ((kslot ^ (krow & 15)) * 8),
                  Kt + cbase * 8);
      const int vd = ck >> 3, vslot = ck & 7;
      GLOAD_LDS16(vtb + vbase + (size_t)vd * S_ + kv0 + ((vslot ^ (vd & 7)) * 8),
                  Vt + cbase * 8);
    }
  };

  stage(0, 0);
  asm volatile("s_waitcnt vmcnt(0)" ::: "memory");
  __syncthreads();

  for (int t = 0; t < T; ++t){
    const int cur = t & 1;
    if (t + 1 < T) stage(cur ^ 1, t + 1);

    const u16* Kt = &Klds[cur][0];
    const u16* Vt = &Vlds[cur][0];
    #pragma unroll
    for (int sub = 0; sub < 2; ++sub){
      const int t32 = 2 * t + sub;
      if (t32 <= qc32){
        const bool diag = (t32 == qc32);
        // QK^T (swapped): lane holds 16 scores for q col = r
        f32x16 sc;
        #pragma unroll
        for (int j = 0; j < 16; ++j) sc[j] = 0.f;
        #pragma unroll
        for (int cc = 0; cc < 8; ++cc){
          const int row = sub * 32 + r;
          const int slot = (cc * 2 + hi) ^ (r & 15);
          bf16x8 kf = *reinterpret_cast<const bf16x8*>(&Kt[row * 128 + slot * 8]);
          sc = __builtin_amdgcn_mfma_f32_32x32x16_bf16(kf, qf[cc], sc, 0, 0, 0);
        }
        // p = 2^( tt2*(1 - u/3 + 2u^2/15) ), u = tt2^2*C2
        float p[16];
        #pragma unroll
        for (int reg = 0; reg < 16; ++reg){
          float tt2 = sc[reg] * C1;
          float w   = tt2 * tt2 * C2;
          float qp  = fmaf(w, 0.13333333f, -0.33333333f);
          float y   = fmaf(tt2 * w, qp, tt2);
          float pv  = __builtin_amdgcn_exp2f(y);
          if (diag){
            int kl = (reg & 3) + 8 * (reg >> 2) + 4 * hi;
            if (kl > r) pv = 0.f;
          }
          p[reg] = pv;
          lsum += pv;
        }
        // pack P to bf16; exchange quads across lane^32 -> PV B-fragments
        unsigned a[4], b[4];
        #pragma unroll
        for (int r4 = 0; r4 < 4; ++r4){
          a[r4] = pack_bf16x2(p[r4*4+0], p[r4*4+1]);
          b[r4] = pack_bf16x2(p[r4*4+2], p[r4*4+3]);
        }
        unsigned ra0 = __shfl_xor(hi ? a[0] : a[1], 32);
        unsigned rb0 = __shfl_xor(hi ? b[0] : b[1], 32);
        unsigned ra1 = __shfl_xor(hi ? a[2] : a[3], 32);
        unsigned rb1 = __shfl_xor(hi ? b[2] : b[3], 32);
        unsigned pw[8];
        pw[0] = hi ? ra0 : a[0];  pw[1] = hi ? rb0 : b[0];
        pw[2] = hi ? a[1] : ra0;  pw[3] = hi ? b[1] : rb0;
        pw[4] = hi ? ra1 : a[2];  pw[5] = hi ? rb1 : b[2];
        pw[6] = hi ? a[3] : ra1;  pw[7] = hi ? b[3] : rb1;
        bf16x8 pb0, pb1;
        __builtin_memcpy(&pb0, &pw[0], 16);
        __builtin_memcpy(&pb1, &pw[4], 16);
        // PV: O^T += V^T . P   (V slots: sub*4+hi, sub*4+2+hi; ^ (d&7))
        #pragma unroll
        for (int i = 0; i < 4; ++i){
          const int d  = i * 32 + r;
          const int sw = d & 7;
          bf16x8 vf0 = *reinterpret_cast<const bf16x8*>(
              &Vt[d * 64 + (((sub * 4 + hi) ^ sw) * 8)]);
          oacc[i] = __builtin_amdgcn_mfma_f32_32x32x16_bf16(vf0, pb0, oacc[i], 0, 0, 0);
          bf16x8 vf1 = *reinterpret_cast<const bf16x8*>(
              &Vt[d * 64 + (((sub * 4 + 2 + hi) ^ sw) * 8)]);
          oacc[i] = __builtin_amdgcn_mfma_f32_32x32x16_bf16(vf1, pb1, oacc[i], 0, 0, 0);
        }
      }
    }
    asm volatile("s_waitcnt vmcnt(0)" ::: "memory");
    __syncthreads();
  }

  float lt = lsum + __shfl_xor(lsum, 32);
  float linv = 1.0f / (1.0f + lt);       // +1 = sink term exp(-m), m=0

  // write: row q = qc+r, dv = i*32 + r4*8 + hi*4 + (0..3)
  const int b = bh >> 4, h = bh & 15;
  u16* orow = ob + ((size_t)(b * S_ + qc + r)) * D_ + h * HD_;
  #pragma unroll
  for (int i = 0; i < 4; ++i){
    #pragma unroll
    for (int r4 = 0; r4 < 4; ++r4){
      ushort4 st;
      st.x = f2bf(oacc[i][r4*4+0] * linv);
      st.y = f2bf(oacc[i][r4*4+1] * linv);
      st.z = f2bf(oacc[i][r4*4+2] * linv);
      st.w = f2bf(oacc[i][r4*4+3] * linv);
      *reinterpret_cast<ushort4*>(orow + i*32 + r4*8 + hi*4) = st;
    }
  }
}

extern "C" void kernel_launch(void* const* d_in, const int* in_sizes, int n_in,
                              void* d_out, int out_size, void* d_ws, size_t ws_size,
                              hipStream_t stream){
  const float* x  = (const float*)d_in[0];
  const float* Wq = (const float*)d_in[1];
  const float* Wk = (const float*)d_in[2];
  const float* Wv = (const float*)d_in[3];
  const float* Wo = (const float*)d_in[4];
  float* out = (float*)d_out;
  char* ws = (char*)d_ws;

  // workspace layout (112 MB total)
  u16* xb   = (u16*)(ws);                      // 16 MB  x bf16 [4096][2048]
  u16* wtq  = (u16*)(ws + (size_t)(16u << 20));//  8 MB  Wq^T bf16 [N][K]
  u16* wtk  = (u16*)(ws + (size_t)(24u << 20));
  u16* wtv  = (u16*)(ws + (size_t)(32u << 20));
  u16* wto  = (u16*)(ws + (size_t)(40u << 20));
  u16* qbuf = (u16*)(ws + (size_t)(48u << 20));// 16 MB  [bh][s][128]
  u16* kbuf = (u16*)(ws + (size_t)(64u << 20));// 16 MB  [bh][s][128]
  u16* vtb  = (u16*)(ws + (size_t)(80u << 20));// 16 MB  [bh][128][s]
  u16* atb  = (u16*)(ws + (size_t)(96u << 20));// 16 MB  [b*S+s][h*128+d]

  cast_x_kernel<<<8192, 256, 0, stream>>>(x, xb);
  wtrans_kernel<<<dim3(64, 64, 4), 256, 0, stream>>>(Wq, Wk, Wv, Wo, wtq, wtk, wtv, wto);
  gemm128_kernel<0><<<dim3(32, 48), 256, 0, stream>>>(xb, wtq, wtk, wtv,
                                                      qbuf, kbuf, vtb, nullptr);
  rope_kernel<<<16384, 256, 0, stream>>>(qbuf, kbuf);
  // grid: bh fastest -> all 16 blocks of a bh land on XCD bh%8
  attn6_kernel<<<dim3(32, 16), 256, 0, stream>>>(qbuf, kbuf, vtb, atb);
  gemm128_kernel<1><<<dim3(32, 16), 256, 0, stream>>>(atb, wto, nullptr, nullptr,
                                                      nullptr, nullptr, nullptr, out);
}

// Round 11
// 272.571 us; speedup vs baseline: 1.2654x; 1.0077x over previous
//
#include <hip/hip_runtime.h>
#include <hip/hip_bf16.h>

// Problem: B=2, S=2048, D=2048, H=16, HD=128
#define B_  2
#define S_  2048
#define D_  2048
#define H_  16
#define HD_ 128

typedef unsigned short u16;
typedef __attribute__((ext_vector_type(8))) short bf16x8;
typedef __attribute__((ext_vector_type(4))) float f32x4;
typedef __attribute__((ext_vector_type(16))) float f32x16;

#define GLOAD_LDS16(g, l)                                                     \
  __builtin_amdgcn_global_load_lds(                                           \
      (const __attribute__((address_space(1))) void*)(g),                     \
      (__attribute__((address_space(3))) void*)(l), 16, 0, 0)

__device__ __forceinline__ u16 f2bf(float f){
  unsigned u; __builtin_memcpy(&u, &f, 4);
  u += 0x7fffu + ((u >> 16) & 1u);     // round-to-nearest-even
  return (u16)(u >> 16);
}
__device__ __forceinline__ float bf2f(u16 h){
  unsigned u = ((unsigned)h) << 16; float f; __builtin_memcpy(&f, &u, 4); return f;
}
__device__ __forceinline__ unsigned pack_bf16x2(float lo, float hi){
  __hip_bfloat162 h2 = __float22bfloat162_rn(float2{lo, hi});  // v_cvt_pk_bf16_f32
  unsigned u; __builtin_memcpy(&u, &h2, 4); return u;
}

// ---------------- cast x (fp32 -> bf16) ----------------
__global__ void cast_x_kernel(const float* __restrict__ x, u16* __restrict__ xb){
  int i = blockIdx.x * 256 + threadIdx.x;            // 2,097,152 float4s
  float4 v = reinterpret_cast<const float4*>(x)[i];
  ushort4 o; o.x = f2bf(v.x); o.y = f2bf(v.y); o.z = f2bf(v.z); o.w = f2bf(v.w);
  reinterpret_cast<ushort4*>(xb)[i] = o;
}

// ---------------- transpose + cast weights: Wt[n][k] = W[k][n] ----------------
__global__ void wtrans_kernel(const float* __restrict__ w0, const float* __restrict__ w1,
                              const float* __restrict__ w2, const float* __restrict__ w3,
                              u16* __restrict__ o0, u16* __restrict__ o1,
                              u16* __restrict__ o2, u16* __restrict__ o3){
  __shared__ float t[32][33];
  const float* src; u16* dst;
  switch (blockIdx.z){
    case 0:  src = w0; dst = o0; break;
    case 1:  src = w1; dst = o1; break;
    case 2:  src = w2; dst = o2; break;
    default: src = w3; dst = o3; break;
  }
  int j0 = blockIdx.x * 32, i0 = blockIdx.y * 32;
  int tx = threadIdx.x & 31, ty = threadIdx.x >> 5;   // 256 thr: 32 x 8
  #pragma unroll
  for (int rr = 0; rr < 4; ++rr)
    t[ty + rr*8][tx] = src[(size_t)(i0 + ty + rr*8) * D_ + j0 + tx];
  __syncthreads();
  #pragma unroll
  for (int rr = 0; rr < 4; ++rr)
    dst[(size_t)(j0 + ty + rr*8) * D_ + i0 + tx] = f2bf(t[tx][ty + rr*8]);
}

// ---------------- 128x128 bf16 GEMM, BK=64, 4 waves, 16x16x32 MFMA ----------------
// LDS [128][64] u16 (128B rows) + 16B-slot XOR swizzle slot^=(row&7) on BOTH the
// pre-swizzled global_load_lds source (linear dest) and the ds_read side
// (R9-measured: 0 bank conflicts). Grid 2D, m-tile fastest (XCD = m%8).
// MODE 0: QKV fused over grid.y (48 n-tiles). q/k epilogue applies RoPE IN-KERNEL:
//   wc=0 waves hold d in [0,64), wc=1 hold d+64 at identical (i,j,e,g,r); wc=1
//   deposits acc into the freed As/Bs LDS, one barrier, wc=0 rotates + stores both
//   halves. v epilogue: transposed bf16 scatter. MODE 1: O-projection, fp32 out.
template<int MODE>
__global__ __launch_bounds__(256) void gemm128_kernel(
    const u16* __restrict__ A,
    const u16* __restrict__ B0, const u16* __restrict__ B1, const u16* __restrict__ B2,
    u16* __restrict__ qb, u16* __restrict__ kb, u16* __restrict__ vtb,
    float* __restrict__ outp)
{
  constexpr int K = 2048;
  __shared__ u16 As[128 * 64];   // 16 KB
  __shared__ u16 Bs[128 * 64];   // 16 KB
  int m0 = blockIdx.x * 128;
  int by = blockIdx.y;
  int which, n0;
  const u16* Bmat;
  if (MODE == 0){ which = by >> 4; n0 = (by & 15) * 128;
                  Bmat = (which == 0) ? B0 : ((which == 1) ? B1 : B2); }
  else          { which = 0; n0 = by * 128; Bmat = B0; }

  int tid  = threadIdx.x;
  int lane = tid & 63;
  int wid  = tid >> 6;
  int wr = wid >> 1, wc = wid & 1;        // 2x2 waves -> 64x64 each
  int g = lane >> 4, r = lane & 15;
  const int sx = r & 7;

  f32x4 zero = {0.f, 0.f, 0.f, 0.f};
  f32x4 acc[4][4];
  #pragma unroll
  for (int i = 0; i < 4; ++i)
    #pragma unroll
    for (int j = 0; j < 4; ++j) acc[i][j] = zero;

  for (int kt = 0; kt < K; kt += 64){
    // stage A,B 128x64 tiles (16 KB each): 1024 chunks, 4 per thread per matrix
    #pragma unroll
    for (int j = 0; j < 4; ++j){
      int cbase = j * 256 + wid * 64;           // wave-uniform LDS chunk base
      int c  = cbase + lane;
      int row = c >> 3, sl = c & 7;
      GLOAD_LDS16(&A[(size_t)(m0 + row) * K + kt + ((sl ^ (row & 7)) * 8)],
                  &As[cbase * 8]);
      GLOAD_LDS16(&Bmat[(size_t)(n0 + row) * K + kt + ((sl ^ (row & 7)) * 8)],
                  &Bs[cbase * 8]);
    }
    asm volatile("s_waitcnt vmcnt(0)" ::: "memory");
    __syncthreads();
    #pragma unroll
    for (int kk = 0; kk < 2; ++kk){
      bf16x8 af[4], bfr[4];
      #pragma unroll
      for (int i = 0; i < 4; ++i)
        af[i]  = *reinterpret_cast<bf16x8*>(
            &As[(wr*64 + i*16 + r) * 64 + (((kk*4 + g) ^ sx) * 8)]);
      #pragma unroll
      for (int i = 0; i < 4; ++i)
        bfr[i] = *reinterpret_cast<bf16x8*>(
            &Bs[(wc*64 + i*16 + r) * 64 + (((kk*4 + g) ^ sx) * 8)]);
      #pragma unroll
      for (int i = 0; i < 4; ++i)
        #pragma unroll
        for (int j = 0; j < 4; ++j)
          acc[i][j] = __builtin_amdgcn_mfma_f32_16x16x32_bf16(af[i], bfr[j], acc[i][j], 0, 0, 0);
    }
    __syncthreads();
  }

  // ---------------- epilogue; C layout: col = lane&15, row = (lane>>4)*4 + e ----
  if (MODE == 0 && which < 2){
    // ---- q/k with fused RoPE ----
    // exchange buffer: 64x64 f32 per wr-pair (reuses As for wr=0, Bs for wr=1);
    // j-slot XOR'd by (row>>2)&3 to keep f32 column writes 2-way-or-better.
    float* xch = (wr == 0) ? reinterpret_cast<float*>(As)
                           : reinterpret_cast<float*>(Bs);
    if (wc == 1){
      #pragma unroll
      for (int i = 0; i < 4; ++i)
        #pragma unroll
        for (int j = 0; j < 4; ++j)
          #pragma unroll
          for (int e = 0; e < 4; ++e){
            int row = i*16 + g*4 + e;
            int sj = j ^ ((row >> 2) & 3);
            xch[row * 64 + sj * 16 + r] = acc[i][j][e];
          }
    }
    __syncthreads();
    if (wc == 0){
      u16* dstb = (which == 0) ? qb : kb;
      const int h  = n0 >> 7;
      const int b  = m0 >> 11;
      const int bh = b * H_ + h;
      const float NEG_L2 = -13.287712379549449f / 64.f;   // -log2(1e4)*2/128
      #pragma unroll
      for (int j = 0; j < 4; ++j){
        int dlo = j*16 + r;                      // d in [0,64)
        float inv = exp2f((float)dlo * NEG_L2);
        #pragma unroll
        for (int i = 0; i < 4; ++i){
          int row0 = m0 + wr*64 + i*16 + g*4;
          #pragma unroll
          for (int e = 0; e < 4; ++e){
            int s0 = (row0 + e) & (S_ - 1);
            float ang = (float)s0 * inv;
            float sn = __sinf(ang), cs = __cosf(ang);
            int row = i*16 + g*4 + e;
            int sj = j ^ ((row >> 2) & 3);
            float x1 = acc[i][j][e];
            float x2 = xch[row * 64 + sj * 16 + r];
            size_t base = ((size_t)bh * S_ + s0) * HD_;
            dstb[base + dlo]      = f2bf(x1 * cs - x2 * sn);
            dstb[base + 64 + dlo] = f2bf(x2 * cs + x1 * sn);
          }
        }
      }
    }
  } else {
    #pragma unroll
    for (int i = 0; i < 4; ++i){
      int row0 = m0 + wr*64 + i*16 + g*4;
      int b  = row0 >> 11, s0 = row0 & (S_ - 1);
      #pragma unroll
      for (int j = 0; j < 4; ++j){
        int col = n0 + wc*64 + j*16 + r;
        if (MODE == 1){
          #pragma unroll
          for (int e = 0; e < 4; ++e)
            outp[(size_t)(row0 + e) * D_ + col] = acc[i][j][e];
        } else {  // which == 2: v, transposed bf16 scatter
          int h = col >> 7, d = col & 127;
          int bh = b * H_ + h;
          ushort4 pk;
          pk.x = f2bf(acc[i][j][0]); pk.y = f2bf(acc[i][j][1]);
          pk.z = f2bf(acc[i][j][2]); pk.w = f2bf(acc[i][j][3]);
          *reinterpret_cast<ushort4*>(&vtb[((size_t)bh * HD_ + d) * S_ + s0]) = pk;
        }
      }
    }
  }
}

// ---------------- attention v6: flash LDS K/V, KVBLK=64, double-buffered ----------
// exp2-domain softmax: p = 2^y, y = tt2*(1 - u/3 + 2u^2/15), tt2 = s*SCALE*log2e,
// u = (s*SCALE/50)^2 = tt2^2*C2.
__global__ __launch_bounds__(256) void attn6_kernel(
  const u16* __restrict__ qbuf, const u16* __restrict__ kbuf,
  const u16* __restrict__ vtb,  u16* __restrict__ ob)
{
  __shared__ u16 Klds[2][64 * 128];   // 16 KB per buffer
  __shared__ u16 Vlds[2][128 * 64];   // 16 KB per buffer

  const int lane = threadIdx.x & 63;
  const int wid  = threadIdx.x >> 6;     // 0..3 = q-chunk within block
  const int r    = lane & 31;
  const int hi   = lane >> 5;
  const int bh   = blockIdx.x;
  const int qblk = 15 - blockIdx.y;      // heavy blocks dispatched first
  const int qc   = qblk * 128 + wid * 32;
  const int qc32 = qc >> 5;              // diagonal 32-subtile index
  const int T    = 2 * qblk + 2;         // 64-key tiles staged by the block

  const float C1 = 0.12751757f;          // (1/sqrt(128)) * log2(e)
  const float C2 = 1.9218114e-4f;        // (ln2/50)^2

  const size_t sbase = (size_t)bh * S_ * HD_;
  const size_t vbase = (size_t)bh * HD_ * S_;

  // Q fragments: lane holds Q[qc+r][d = cc*16 + hi*8 + j]
  bf16x8 qf[8];
  {
    const u16* qrow = qbuf + sbase + (size_t)(qc + r) * HD_ + hi * 8;
    #pragma unroll
    for (int cc = 0; cc < 8; ++cc)
      qf[cc] = *reinterpret_cast<const bf16x8*>(qrow + cc * 16);
  }

  f32x16 oacc[4];
  #pragma unroll
  for (int i = 0; i < 4; ++i)
    #pragma unroll
    for (int j = 0; j < 16; ++j) oacc[i][j] = 0.f;
  float lsum = 0.f;

  // stage 64-key tile t: K 16KB + V 16KB; 8 gload_lds/thread
  auto stage = [&](int buf, int t){
    const int kv0 = t * 64;
    u16* Kt = &Klds[buf][0];
    u16* Vt = &Vlds[buf][0];
    #pragma unroll
    for (int j = 0; j < 4; ++j){
      const int cbase = j * 256 + wid * 64;   // wave-uniform
      const int ck = cbase + lane;
      const int krow = ck >> 4, kslot = ck & 15;
      GLOAD_LDS16(kbuf + sbase + (size_t)(kv0 + krow) * HD_ + ((kslot ^ (krow & 15)) * 8),
                  Kt + cbase * 8);
      const int vd = ck >> 3, vslot = ck & 7;
      GLOAD_LDS16(vtb + vbase + (size_t)vd * S_ + kv0 + ((vslot ^ (vd & 7)) * 8),
                  Vt + cbase * 8);
    }
  };

  stage(0, 0);
  asm volatile("s_waitcnt vmcnt(0)" ::: "memory");
  __syncthreads();

  for (int t = 0; t < T; ++t){
    const int cur = t & 1;
    if (t + 1 < T) stage(cur ^ 1, t + 1);

    const u16* Kt = &Klds[cur][0];
    const u16* Vt = &Vlds[cur][0];
    #pragma unroll
    for (int sub = 0; sub < 2; ++sub){
      const int t32 = 2 * t + sub;
      if (t32 <= qc32){
        const bool diag = (t32 == qc32);
        // QK^T (swapped): lane holds 16 scores for q col = r
        f32x16 sc;
        #pragma unroll
        for (int j = 0; j < 16; ++j) sc[j] = 0.f;
        #pragma unroll
        for (int cc = 0; cc < 8; ++cc){
          const int row = sub * 32 + r;
          const int slot = (cc * 2 + hi) ^ (r & 15);
          bf16x8 kf = *reinterpret_cast<const bf16x8*>(&Kt[row * 128 + slot * 8]);
          sc = __builtin_amdgcn_mfma_f32_32x32x16_bf16(kf, qf[cc], sc, 0, 0, 0);
        }
        // p = 2^( tt2*(1 - u/3 + 2u^2/15) ), u = tt2^2*C2
        float p[16];
        #pragma unroll
        for (int reg = 0; reg < 16; ++reg){
          float tt2 = sc[reg] * C1;
          float w   = tt2 * tt2 * C2;
          float qp  = fmaf(w, 0.13333333f, -0.33333333f);
          float y   = fmaf(tt2 * w, qp, tt2);
          float pv  = __builtin_amdgcn_exp2f(y);
          if (diag){
            int kl = (reg & 3) + 8 * (reg >> 2) + 4 * hi;
            if (kl > r) pv = 0.f;
          }
          p[reg] = pv;
          lsum += pv;
        }
        // pack P to bf16; exchange quads across lane^32 -> PV B-fragments
        unsigned a[4], b[4];
        #pragma unroll
        for (int r4 = 0; r4 < 4; ++r4){
          a[r4] = pack_bf16x2(p[r4*4+0], p[r4*4+1]);
          b[r4] = pack_bf16x2(p[r4*4+2], p[r4*4+3]);
        }
        unsigned ra0 = __shfl_xor(hi ? a[0] : a[1], 32);
        unsigned rb0 = __shfl_xor(hi ? b[0] : b[1], 32);
        unsigned ra1 = __shfl_xor(hi ? a[2] : a[3], 32);
        unsigned rb1 = __shfl_xor(hi ? b[2] : b[3], 32);
        unsigned pw[8];
        pw[0] = hi ? ra0 : a[0];  pw[1] = hi ? rb0 : b[0];
        pw[2] = hi ? a[1] : ra0;  pw[3] = hi ? b[1] : rb0;
        pw[4] = hi ? ra1 : a[2];  pw[5] = hi ? rb1 : b[2];
        pw[6] = hi ? a[3] : ra1;  pw[7] = hi ? b[3] : rb1;
        bf16x8 pb0, pb1;
        __builtin_memcpy(&pb0, &pw[0], 16);
        __builtin_memcpy(&pb1, &pw[4], 16);
        // PV: O^T += V^T . P   (V slots: sub*4+hi, sub*4+2+hi; ^ (d&7))
        #pragma unroll
        for (int i = 0; i < 4; ++i){
          const int d  = i * 32 + r;
          const int sw = d & 7;
          bf16x8 vf0 = *reinterpret_cast<const bf16x8*>(
              &Vt[d * 64 + (((sub * 4 + hi) ^ sw) * 8)]);
          oacc[i] = __builtin_amdgcn_mfma_f32_32x32x16_bf16(vf0, pb0, oacc[i], 0, 0, 0);
          bf16x8 vf1 = *reinterpret_cast<const bf16x8*>(
              &Vt[d * 64 + (((sub * 4 + 2 + hi) ^ sw) * 8)]);
          oacc[i] = __builtin_amdgcn_mfma_f32_32x32x16_bf16(vf1, pb1, oacc[i], 0, 0, 0);
        }
      }
    }
    asm volatile("s_waitcnt vmcnt(0)" ::: "memory");
    __syncthreads();
  }

  float lt = lsum + __shfl_xor(lsum, 32);
  float linv = 1.0f / (1.0f + lt);       // +1 = sink term exp(-m), m=0

  // write: row q = qc+r, dv = i*32 + r4*8 + hi*4 + (0..3)
  const int b = bh >> 4, h = bh & 15;
  u16* orow = ob + ((size_t)(b * S_ + qc + r)) * D_ + h * HD_;
  #pragma unroll
  for (int i = 0; i < 4; ++i){
    #pragma unroll
    for (int r4 = 0; r4 < 4; ++r4){
      ushort4 st;
      st.x = f2bf(oacc[i][r4*4+0] * linv);
      st.y = f2bf(oacc[i][r4*4+1] * linv);
      st.z = f2bf(oacc[i][r4*4+2] * linv);
      st.w = f2bf(oacc[i][r4*4+3] * linv);
      *reinterpret_cast<ushort4*>(orow + i*32 + r4*8 + hi*4) = st;
    }
  }
}

extern "C" void kernel_launch(void* const* d_in, const int* in_sizes, int n_in,
                              void* d_out, int out_size, void* d_ws, size_t ws_size,
                              hipStream_t stream){
  const float* x  = (const float*)d_in[0];
  const float* Wq = (const float*)d_in[1];
  const float* Wk = (const float*)d_in[2];
  const float* Wv = (const float*)d_in[3];
  const float* Wo = (const float*)d_in[4];
  float* out = (float*)d_out;
  char* ws = (char*)d_ws;

  // workspace layout (112 MB total)
  u16* xb   = (u16*)(ws);                      // 16 MB  x bf16 [4096][2048]
  u16* wtq  = (u16*)(ws + (size_t)(16u << 20));//  8 MB  Wq^T bf16 [N][K]
  u16* wtk  = (u16*)(ws + (size_t)(24u << 20));
  u16* wtv  = (u16*)(ws + (size_t)(32u << 20));
  u16* wto  = (u16*)(ws + (size_t)(40u << 20));
  u16* qbuf = (u16*)(ws + (size_t)(48u << 20));// 16 MB  [bh][s][128] (post-RoPE)
  u16* kbuf = (u16*)(ws + (size_t)(64u << 20));// 16 MB  [bh][s][128] (post-RoPE)
  u16* vtb  = (u16*)(ws + (size_t)(80u << 20));// 16 MB  [bh][128][s]
  u16* atb  = (u16*)(ws + (size_t)(96u << 20));// 16 MB  [b*S+s][h*128+d]

  cast_x_kernel<<<8192, 256, 0, stream>>>(x, xb);
  wtrans_kernel<<<dim3(64, 64, 4), 256, 0, stream>>>(Wq, Wk, Wv, Wo, wtq, wtk, wtv, wto);
  gemm128_kernel<0><<<dim3(32, 48), 256, 0, stream>>>(xb, wtq, wtk, wtv,
                                                      qbuf, kbuf, vtb, nullptr);
  // grid: bh fastest -> all 16 blocks of a bh land on XCD bh%8
  attn6_kernel<<<dim3(32, 16), 256, 0, stream>>>(qbuf, kbuf, vtb, atb);
  gemm128_kernel<1><<<dim3(32, 16), 256, 0, stream>>>(atb, wto, nullptr, nullptr,
                                                      nullptr, nullptr, nullptr, out);
}

// Round 12
// 268.701 us; speedup vs baseline: 1.2836x; 1.0144x over previous
//
#include <hip/hip_runtime.h>
#include <hip/hip_bf16.h>

// Problem: B=2, S=2048, D=2048, H=16, HD=128
#define B_  2
#define S_  2048
#define D_  2048
#define H_  16
#define HD_ 128

typedef unsigned short u16;
typedef __attribute__((ext_vector_type(8))) short bf16x8;
typedef __attribute__((ext_vector_type(4))) float f32x4;
typedef __attribute__((ext_vector_type(16))) float f32x16;

#define GLOAD_LDS16(g, l)                                                     \
  __builtin_amdgcn_global_load_lds(                                           \
      (const __attribute__((address_space(1))) void*)(g),                     \
      (__attribute__((address_space(3))) void*)(l), 16, 0, 0)

__device__ __forceinline__ u16 f2bf(float f){
  unsigned u; __builtin_memcpy(&u, &f, 4);
  u += 0x7fffu + ((u >> 16) & 1u);     // round-to-nearest-even
  return (u16)(u >> 16);
}
__device__ __forceinline__ float bf2f(u16 h){
  unsigned u = ((unsigned)h) << 16; float f; __builtin_memcpy(&f, &u, 4); return f;
}
__device__ __forceinline__ unsigned pack_bf16x2(float lo, float hi){
  __hip_bfloat162 h2 = __float22bfloat162_rn(float2{lo, hi});  // v_cvt_pk_bf16_f32
  unsigned u; __builtin_memcpy(&u, &h2, 4); return u;
}

// ---------------- cast x (fp32 -> bf16) ----------------
__global__ void cast_x_kernel(const float* __restrict__ x, u16* __restrict__ xb){
  int i = blockIdx.x * 256 + threadIdx.x;            // 2,097,152 float4s
  float4 v = reinterpret_cast<const float4*>(x)[i];
  ushort4 o; o.x = f2bf(v.x); o.y = f2bf(v.y); o.z = f2bf(v.z); o.w = f2bf(v.w);
  reinterpret_cast<ushort4*>(xb)[i] = o;
}

// ---------------- transpose + cast weights: Wt[n][k] = W[k][n] ----------------
__global__ void wtrans_kernel(const float* __restrict__ w0, const float* __restrict__ w1,
                              const float* __restrict__ w2, const float* __restrict__ w3,
                              u16* __restrict__ o0, u16* __restrict__ o1,
                              u16* __restrict__ o2, u16* __restrict__ o3){
  __shared__ float t[32][33];
  const float* src; u16* dst;
  switch (blockIdx.z){
    case 0:  src = w0; dst = o0; break;
    case 1:  src = w1; dst = o1; break;
    case 2:  src = w2; dst = o2; break;
    default: src = w3; dst = o3; break;
  }
  int j0 = blockIdx.x * 32, i0 = blockIdx.y * 32;
  int tx = threadIdx.x & 31, ty = threadIdx.x >> 5;   // 256 thr: 32 x 8
  #pragma unroll
  for (int rr = 0; rr < 4; ++rr)
    t[ty + rr*8][tx] = src[(size_t)(i0 + ty + rr*8) * D_ + j0 + tx];
  __syncthreads();
  #pragma unroll
  for (int rr = 0; rr < 4; ++rr)
    dst[(size_t)(j0 + ty + rr*8) * D_ + i0 + tx] = f2bf(t[tx][ty + rr*8]);
}

// ---------------- 128x128 bf16 GEMM, BK=64, 4 waves, 16x16x32 MFMA ----------------
// LDS [128][64] u16 (128B rows) + 16B-slot XOR swizzle slot^=(row&7) on BOTH the
// pre-swizzled global_load_lds source (linear dest) and the ds_read side
// (R9-measured: 0 bank conflicts). Grid 2D, m-tile fastest (XCD = m%8).
// MODE 0: QKV fused over grid.y (48 n-tiles). q/k epilogue applies RoPE via
// dump-then-rotate: all waves dump acc as bf16 into the freed 32KB LDS (acc dies
// -> epilogue register peak collapses to the main loop's), barrier, then 256
// threads rotate cooperatively (d = tid&63 fixed -> one exp2f/thread; wave walks
// uniform rows; coalesced 128B global stores). v: transposed bf16 scatter.
// MODE 1: O-projection, fp32 out.
template<int MODE>
__global__ __launch_bounds__(256) void gemm128_kernel(
    const u16* __restrict__ A,
    const u16* __restrict__ B0, const u16* __restrict__ B1, const u16* __restrict__ B2,
    u16* __restrict__ qb, u16* __restrict__ kb, u16* __restrict__ vtb,
    float* __restrict__ outp)
{
  constexpr int K = 2048;
  __shared__ u16 lds[2][128 * 64];   // [0]=A tile, [1]=B tile; 32 KB total
  u16* As = &lds[0][0];
  u16* Bs = &lds[1][0];
  int m0 = blockIdx.x * 128;
  int by = blockIdx.y;
  int which, n0;
  const u16* Bmat;
  if (MODE == 0){ which = by >> 4; n0 = (by & 15) * 128;
                  Bmat = (which == 0) ? B0 : ((which == 1) ? B1 : B2); }
  else          { which = 0; n0 = by * 128; Bmat = B0; }

  int tid  = threadIdx.x;
  int lane = tid & 63;
  int wid  = tid >> 6;
  int wr = wid >> 1, wc = wid & 1;        // 2x2 waves -> 64x64 each
  int g = lane >> 4, r = lane & 15;
  const int sx = r & 7;

  f32x4 zero = {0.f, 0.f, 0.f, 0.f};
  f32x4 acc[4][4];
  #pragma unroll
  for (int i = 0; i < 4; ++i)
    #pragma unroll
    for (int j = 0; j < 4; ++j) acc[i][j] = zero;

  for (int kt = 0; kt < K; kt += 64){
    // stage A,B 128x64 tiles (16 KB each): 1024 chunks, 4 per thread per matrix
    #pragma unroll
    for (int j = 0; j < 4; ++j){
      int cbase = j * 256 + wid * 64;           // wave-uniform LDS chunk base
      int c  = cbase + lane;
      int row = c >> 3, sl = c & 7;
      GLOAD_LDS16(&A[(size_t)(m0 + row) * K + kt + ((sl ^ (row & 7)) * 8)],
                  &As[cbase * 8]);
      GLOAD_LDS16(&Bmat[(size_t)(n0 + row) * K + kt + ((sl ^ (row & 7)) * 8)],
                  &Bs[cbase * 8]);
    }
    asm volatile("s_waitcnt vmcnt(0)" ::: "memory");
    __syncthreads();
    #pragma unroll
    for (int kk = 0; kk < 2; ++kk){
      bf16x8 af[4], bfr[4];
      #pragma unroll
      for (int i = 0; i < 4; ++i)
        af[i]  = *reinterpret_cast<bf16x8*>(
            &As[(wr*64 + i*16 + r) * 64 + (((kk*4 + g) ^ sx) * 8)]);
      #pragma unroll
      for (int i = 0; i < 4; ++i)
        bfr[i] = *reinterpret_cast<bf16x8*>(
            &Bs[(wc*64 + i*16 + r) * 64 + (((kk*4 + g) ^ sx) * 8)]);
      #pragma unroll
      for (int i = 0; i < 4; ++i)
        #pragma unroll
        for (int j = 0; j < 4; ++j)
          acc[i][j] = __builtin_amdgcn_mfma_f32_16x16x32_bf16(af[i], bfr[j], acc[i][j], 0, 0, 0);
    }
    __syncthreads();
  }

  // ---------------- epilogue; C layout: col = lane&15, row = (lane>>4)*4 + e ----
  if (MODE == 0 && which < 2){
    // ---- q/k with fused RoPE: dump acc (bf16) -> LDS [128][128], then rotate ----
    u16* xch = &lds[0][0];   // 128 rows x 128 cols u16 = 32 KB
    #pragma unroll
    for (int i = 0; i < 4; ++i)
      #pragma unroll
      for (int e = 0; e < 4; ++e){
        int row = wr*64 + i*16 + g*4 + e;
        int sj  = ((row >> 2) & 7) << 3;
        #pragma unroll
        for (int j = 0; j < 4; ++j){
          int col = wc*64 + j*16 + r;
          xch[row * 128 + (col ^ sj)] = f2bf(acc[i][j][e]);
        }
      }
    __syncthreads();
    {
      u16* dstb = (which == 0) ? qb : kb;
      const int h  = n0 >> 7;
      const int b  = m0 >> 11;
      const int bh = b * H_ + h;
      const int d  = tid & 63;             // rotation pair (d, d+64)
      const int wg = tid >> 6;             // wave -> 32-row slab
      const float NEG_L2 = -13.287712379549449f / 64.f;   // -log2(1e4)*2/128
      const float inv = exp2f((float)d * NEG_L2);
      const int s_base = m0 & (S_ - 1);
      for (int k = 0; k < 32; ++k){
        int row = wg * 32 + k;             // wave-uniform
        int s0  = s_base + row;
        float ang = (float)s0 * inv;
        float sn = __sinf(ang), cs = __cosf(ang);
        int sj = ((row >> 2) & 7) << 3;
        float x1 = bf2f(xch[row * 128 + (d ^ sj)]);
        float x2 = bf2f(xch[row * 128 + 64 + (d ^ sj)]);
        size_t base = ((size_t)bh * S_ + s0) * HD_;
        dstb[base + d]      = f2bf(x1 * cs - x2 * sn);
        dstb[base + 64 + d] = f2bf(x2 * cs + x1 * sn);
      }
    }
  } else {
    #pragma unroll
    for (int i = 0; i < 4; ++i){
      int row0 = m0 + wr*64 + i*16 + g*4;
      int b  = row0 >> 11, s0 = row0 & (S_ - 1);
      #pragma unroll
      for (int j = 0; j < 4; ++j){
        int col = n0 + wc*64 + j*16 + r;
        if (MODE == 1){
          #pragma unroll
          for (int e = 0; e < 4; ++e)
            outp[(size_t)(row0 + e) * D_ + col] = acc[i][j][e];
        } else {  // which == 2: v, transposed bf16 scatter
          int h = col >> 7, d = col & 127;
          int bh = b * H_ + h;
          ushort4 pk;
          pk.x = f2bf(acc[i][j][0]); pk.y = f2bf(acc[i][j][1]);
          pk.z = f2bf(acc[i][j][2]); pk.w = f2bf(acc[i][j][3]);
          *reinterpret_cast<ushort4*>(&vtb[((size_t)bh * HD_ + d) * S_ + s0]) = pk;
        }
      }
    }
  }
}

// ---------------- attention v6: flash LDS K/V, KVBLK=64, double-buffered ----------
// exp2-domain softmax: p = 2^y, y = tt2*(1 - u/3 + 2u^2/15), tt2 = s*SCALE*log2e,
// u = (s*SCALE/50)^2 = tt2^2*C2.
__global__ __launch_bounds__(256) void attn6_kernel(
  const u16* __restrict__ qbuf, const u16* __restrict__ kbuf,
  const u16* __restrict__ vtb,  u16* __restrict__ ob)
{
  __shared__ u16 Klds[2][64 * 128];   // 16 KB per buffer
  __shared__ u16 Vlds[2][128 * 64];   // 16 KB per buffer

  const int lane = threadIdx.x & 63;
  const int wid  = threadIdx.x >> 6;     // 0..3 = q-chunk within block
  const int r    = lane & 31;
  const int hi   = lane >> 5;
  const int bh   = blockIdx.x;
  const int qblk = 15 - blockIdx.y;      // heavy blocks dispatched first
  const int qc   = qblk * 128 + wid * 32;
  const int qc32 = qc >> 5;              // diagonal 32-subtile index
  const int T    = 2 * qblk + 2;         // 64-key tiles staged by the block

  const float C1 = 0.12751757f;          // (1/sqrt(128)) * log2(e)
  const float C2 = 1.9218114e-4f;        // (ln2/50)^2

  const size_t sbase = (size_t)bh * S_ * HD_;
  const size_t vbase = (size_t)bh * HD_ * S_;

  // Q fragments: lane holds Q[qc+r][d = cc*16 + hi*8 + j]
  bf16x8 qf[8];
  {
    const u16* qrow = qbuf + sbase + (size_t)(qc + r) * HD_ + hi * 8;
    #pragma unroll
    for (int cc = 0; cc < 8; ++cc)
      qf[cc] = *reinterpret_cast<const bf16x8*>(qrow + cc * 16);
  }

  f32x16 oacc[4];
  #pragma unroll
  for (int i = 0; i < 4; ++i)
    #pragma unroll
    for (int j = 0; j < 16; ++j) oacc[i][j] = 0.f;
  float lsum = 0.f;

  // stage 64-key tile t: K 16KB + V 16KB; 8 gload_lds/thread
  auto stage = [&](int buf, int t){
    const int kv0 = t * 64;
    u16* Kt = &Klds[buf][0];
    u16* Vt = &Vlds[buf][0];
    #pragma unroll
    for (int j = 0; j < 4; ++j){
      const int cbase = j * 256 + wid * 64;   // wave-uniform
      const int ck = cbase + lane;
      const int krow = ck >> 4, kslot = ck & 15;
      GLOAD_LDS16(kbuf + sbase + (size_t)(kv0 + krow) * HD_ + ((kslot ^ (krow & 15)) * 8),
                  Kt + cbase * 8);
      const int vd = ck >> 3, vslot = ck & 7;
      GLOAD_LDS16(vtb + vbase + (size_t)vd * S_ + kv0 + ((vslot ^ (vd & 7)) * 8),
                  Vt + cbase * 8);
    }
  };

  stage(0, 0);
  asm volatile("s_waitcnt vmcnt(0)" ::: "memory");
  __syncthreads();

  for (int t = 0; t < T; ++t){
    const int cur = t & 1;
    if (t + 1 < T) stage(cur ^ 1, t + 1);

    const u16* Kt = &Klds[cur][0];
    const u16* Vt = &Vlds[cur][0];
    #pragma unroll
    for (int sub = 0; sub < 2; ++sub){
      const int t32 = 2 * t + sub;
      if (t32 <= qc32){
        const bool diag = (t32 == qc32);
        // QK^T (swapped): lane holds 16 scores for q col = r
        f32x16 sc;
        #pragma unroll
        for (int j = 0; j < 16; ++j) sc[j] = 0.f;
        #pragma unroll
        for (int cc = 0; cc < 8; ++cc){
          const int row = sub * 32 + r;
          const int slot = (cc * 2 + hi) ^ (r & 15);
          bf16x8 kf = *reinterpret_cast<const bf16x8*>(&Kt[row * 128 + slot * 8]);
          sc = __builtin_amdgcn_mfma_f32_32x32x16_bf16(kf, qf[cc], sc, 0, 0, 0);
        }
        // p = 2^( tt2*(1 - u/3 + 2u^2/15) ), u = tt2^2*C2
        float p[16];
        #pragma unroll
        for (int reg = 0; reg < 16; ++reg){
          float tt2 = sc[reg] * C1;
          float w   = tt2 * tt2 * C2;
          float qp  = fmaf(w, 0.13333333f, -0.33333333f);
          float y   = fmaf(tt2 * w, qp, tt2);
          float pv  = __builtin_amdgcn_exp2f(y);
          if (diag){
            int kl = (reg & 3) + 8 * (reg >> 2) + 4 * hi;
            if (kl > r) pv = 0.f;
          }
          p[reg] = pv;
          lsum += pv;
        }
        // pack P to bf16; exchange quads across lane^32 -> PV B-fragments
        unsigned a[4], b[4];
        #pragma unroll
        for (int r4 = 0; r4 < 4; ++r4){
          a[r4] = pack_bf16x2(p[r4*4+0], p[r4*4+1]);
          b[r4] = pack_bf16x2(p[r4*4+2], p[r4*4+3]);
        }
        unsigned ra0 = __shfl_xor(hi ? a[0] : a[1], 32);
        unsigned rb0 = __shfl_xor(hi ? b[0] : b[1], 32);
        unsigned ra1 = __shfl_xor(hi ? a[2] : a[3], 32);
        unsigned rb1 = __shfl_xor(hi ? b[2] : b[3], 32);
        unsigned pw[8];
        pw[0] = hi ? ra0 : a[0];  pw[1] = hi ? rb0 : b[0];
        pw[2] = hi ? a[1] : ra0;  pw[3] = hi ? b[1] : rb0;
        pw[4] = hi ? ra1 : a[2];  pw[5] = hi ? rb1 : b[2];
        pw[6] = hi ? a[3] : ra1;  pw[7] = hi ? b[3] : rb1;
        bf16x8 pb0, pb1;
        __builtin_memcpy(&pb0, &pw[0], 16);
        __builtin_memcpy(&pb1, &pw[4], 16);
        // PV: O^T += V^T . P   (V slots: sub*4+hi, sub*4+2+hi; ^ (d&7))
        #pragma unroll
        for (int i = 0; i < 4; ++i){
          const int d  = i * 32 + r;
          const int sw = d & 7;
          bf16x8 vf0 = *reinterpret_cast<const bf16x8*>(
              &Vt[d * 64 + (((sub * 4 + hi) ^ sw) * 8)]);
          oacc[i] = __builtin_amdgcn_mfma_f32_32x32x16_bf16(vf0, pb0, oacc[i], 0, 0, 0);
          bf16x8 vf1 = *reinterpret_cast<const bf16x8*>(
              &Vt[d * 64 + (((sub * 4 + 2 + hi) ^ sw) * 8)]);
          oacc[i] = __builtin_amdgcn_mfma_f32_32x32x16_bf16(vf1, pb1, oacc[i], 0, 0, 0);
        }
      }
    }
    asm volatile("s_waitcnt vmcnt(0)" ::: "memory");
    __syncthreads();
  }

  float lt = lsum + __shfl_xor(lsum, 32);
  float linv = 1.0f / (1.0f + lt);       // +1 = sink term exp(-m), m=0

  // write: row q = qc+r, dv = i*32 + r4*8 + hi*4 + (0..3)
  const int b = bh >> 4, h = bh & 15;
  u16* orow = ob + ((size_t)(b * S_ + qc + r)) * D_ + h * HD_;
  #pragma unroll
  for (int i = 0; i < 4; ++i){
    #pragma unroll
    for (int r4 = 0; r4 < 4; ++r4){
      ushort4 st;
      st.x = f2bf(oacc[i][r4*4+0] * linv);
      st.y = f2bf(oacc[i][r4*4+1] * linv);
      st.z = f2bf(oacc[i][r4*4+2] * linv);
      st.w = f2bf(oacc[i][r4*4+3] * linv);
      *reinterpret_cast<ushort4*>(orow + i*32 + r4*8 + hi*4) = st;
    }
  }
}

extern "C" void kernel_launch(void* const* d_in, const int* in_sizes, int n_in,
                              void* d_out, int out_size, void* d_ws, size_t ws_size,
                              hipStream_t stream){
  const float* x  = (const float*)d_in[0];
  const float* Wq = (const float*)d_in[1];
  const float* Wk = (const float*)d_in[2];
  const float* Wv = (const float*)d_in[3];
  const float* Wo = (const float*)d_in[4];
  float* out = (float*)d_out;
  char* ws = (char*)d_ws;

  // workspace layout (112 MB total)
  u16* xb   = (u16*)(ws);                      // 16 MB  x bf16 [4096][2048]
  u16* wtq  = (u16*)(ws + (size_t)(16u << 20));//  8 MB  Wq^T bf16 [N][K]
  u16* wtk  = (u16*)(ws + (size_t)(24u << 20));
  u16* wtv  = (u16*)(ws + (size_t)(32u << 20));
  u16* wto  = (u16*)(ws + (size_t)(40u << 20));
  u16* qbuf = (u16*)(ws + (size_t)(48u << 20));// 16 MB  [bh][s][128] (post-RoPE)
  u16* kbuf = (u16*)(ws + (size_t)(64u << 20));// 16 MB  [bh][s][128] (post-RoPE)
  u16* vtb  = (u16*)(ws + (size_t)(80u << 20));// 16 MB  [bh][128][s]
  u16* atb  = (u16*)(ws + (size_t)(96u << 20));// 16 MB  [b*S+s][h*128+d]

  cast_x_kernel<<<8192, 256, 0, stream>>>(x, xb);
  wtrans_kernel<<<dim3(64, 64, 4), 256, 0, stream>>>(Wq, Wk, Wv, Wo, wtq, wtk, wtv, wto);
  gemm128_kernel<0><<<dim3(32, 48), 256, 0, stream>>>(xb, wtq, wtk, wtv,
                                                      qbuf, kbuf, vtb, nullptr);
  // grid: bh fastest -> all 16 blocks of a bh land on XCD bh%8
  attn6_kernel<<<dim3(32, 16), 256, 0, stream>>>(qbuf, kbuf, vtb, atb);
  gemm128_kernel<1><<<dim3(32, 16), 256, 0, stream>>>(atb, wto, nullptr, nullptr,
                                                      nullptr, nullptr, nullptr, out);
}